// Round 1
// baseline (333.097 us; speedup 1.0000x reference)
//
#include <hip/hip_runtime.h>
#include <math.h>

#define KK 49
#define REL 64
#define C1 66
#define CIN 512
#define COUT 512
#define HWTOT 1024
#define EPSV 1e-5f

// workspace float offsets
#define OFF_X1T 0
#define OFF_X2T (OFF_X1T + 4*HWTOT*REL)
#define OFF_X3  (OFF_X2T + 4*HWTOT*REL)
#define OFF_PM  (OFF_X3 + 4*COUT*HWTOT)
#define OFF_A0  (OFF_PM + HWTOT*2)
#define OFF_C0  (OFF_A0 + C1)
#define OFF_A1  (OFF_C0 + C1)
#define OFF_C1V (OFF_A1 + REL)

__device__ __forceinline__ int refl(int m) {
    if (m < 0) m = -m;
    if (m > 31) m = 62 - m;
    return m;
}

__global__ void k_setup(const float* __restrict__ wp, const float* __restrict__ bp,
                        const float* __restrict__ g0, const float* __restrict__ be0,
                        const float* __restrict__ m0, const float* __restrict__ v0,
                        const float* __restrict__ g1, const float* __restrict__ be1,
                        const float* __restrict__ m1, const float* __restrict__ v1,
                        float* __restrict__ ws) {
    int tid = threadIdx.x;
    float* pm = ws + OFF_PM;
    for (int n = tid; n < HWTOT; n += 256) {
        int xx = n & 31, yy = n >> 5;
        float lw = -1.f + (2.f / 31.f) * xx;
        float lh = -1.f + (2.f / 31.f) * yy;
        pm[n * 2 + 0] = wp[0] * lw + wp[1] * lh + bp[0];
        pm[n * 2 + 1] = wp[2] * lw + wp[3] * lh + bp[1];
    }
    if (tid < C1) {
        float a = g0[tid] * rsqrtf(v0[tid] + EPSV);
        ws[OFF_A0 + tid] = a;
        ws[OFF_C0 + tid] = be0[tid] - m0[tid] * a;
    }
    if (tid < REL) {
        float a = g1[tid] * rsqrtf(v1[tid] + EPSV);
        ws[OFF_A1 + tid] = a;
        ws[OFF_C1V + tid] = be1[tid] - m1[tid] * a;
    }
}

// 640x1024x512 GEMM per batch: rows 0..63 -> x1t (transposed), 64..127 -> x2t, 128..639 -> x3
__global__ __launch_bounds__(256) void k_proj(
        const float* __restrict__ x,
        const float* __restrict__ w1, const float* __restrict__ b1,
        const float* __restrict__ w2, const float* __restrict__ b2,
        const float* __restrict__ w3, const float* __restrict__ b3,
        float* __restrict__ ws) {
    __shared__ __align__(16) float As[64 * 17];
    __shared__ __align__(16) float Bs[16 * 64];
    int tid = threadIdx.x;
    int n0 = blockIdx.x * 64;
    int mT = blockIdx.y;
    int b = blockIdx.z;
    int mq = tid >> 4, nq = tid & 15;
    float acc[4][4];
#pragma unroll
    for (int i = 0; i < 4; i++)
#pragma unroll
        for (int j = 0; j < 4; j++) acc[i][j] = 0.f;

    for (int k0 = 0; k0 < CIN; k0 += 16) {
#pragma unroll
        for (int i = 0; i < 4; i++) {
            int t = tid + i * 256;
            int k = t & 15, m = t >> 4;
            int mg = mT * 64 + m;
            const float* Wrow;
            if (mg < 64) Wrow = w1 + mg * CIN;
            else if (mg < 128) Wrow = w2 + (mg - 64) * CIN;
            else Wrow = w3 + (mg - 128) * CIN;
            As[m * 17 + k] = Wrow[k0 + k];
        }
#pragma unroll
        for (int i = 0; i < 4; i++) {
            int t = tid + i * 256;
            int n = t & 63, k = t >> 6;
            Bs[k * 64 + n] = x[(b * CIN + k0 + k) * HWTOT + n0 + n];
        }
        __syncthreads();
#pragma unroll
        for (int k = 0; k < 16; k++) {
            float4 bv = *(const float4*)&Bs[k * 64 + nq * 4];
            float av[4];
#pragma unroll
            for (int i = 0; i < 4; i++) av[i] = As[(mq * 4 + i) * 17 + k];
#pragma unroll
            for (int i = 0; i < 4; i++) {
                acc[i][0] += av[i] * bv.x;
                acc[i][1] += av[i] * bv.y;
                acc[i][2] += av[i] * bv.z;
                acc[i][3] += av[i] * bv.w;
            }
        }
        __syncthreads();
    }
    float* x1t = ws + OFF_X1T;
    float* x2t = ws + OFF_X2T;
    float* x3 = ws + OFF_X3;
#pragma unroll
    for (int i = 0; i < 4; i++) {
        int mg = mT * 64 + mq * 4 + i;
        if (mg < 64) {
            float bias = b1[mg];
#pragma unroll
            for (int j = 0; j < 4; j++) {
                int n = n0 + nq * 4 + j;
                x1t[(b * HWTOT + n) * REL + mg] = acc[i][j] + bias;
            }
        } else if (mg < 128) {
            float bias = b2[mg - 64];
#pragma unroll
            for (int j = 0; j < 4; j++) {
                int n = n0 + nq * 4 + j;
                x2t[(b * HWTOT + n) * REL + (mg - 64)] = acc[i][j] + bias;
            }
        } else {
            float bias = b3[mg - 128];
#pragma unroll
            for (int j = 0; j < 4; j++) {
                int n = n0 + nq * 4 + j;
                x3[(b * COUT + (mg - 128)) * HWTOT + n] = acc[i][j] + bias;
            }
        }
    }
}

// One WG handles (batch, 2 adjacent pixels in one row). 128 threads.
__global__ __launch_bounds__(128) void k_fused(
        const float* __restrict__ wcw1, const float* __restrict__ wcw2,
        const float* __restrict__ bcw2,
        const float* __restrict__ ws, float* __restrict__ out) {
    __shared__ __align__(16) float ldsA[6664];  // t0a [2][49][68]; then s scratch [2][64][49]; then x3 slab [64][61]
    __shared__ __align__(16) float ldsB[6272];  // t1a / wgt  [2][49][64]
    const float* x1t = ws + OFF_X1T;
    const float* x2t = ws + OFF_X2T;
    const float* x3 = ws + OFF_X3;
    const float* pm = ws + OFF_PM;
    const float* a0 = ws + OFF_A0;
    const float* c0 = ws + OFF_C0;
    const float* a1 = ws + OFF_A1;
    const float* c1 = ws + OFF_C1V;

    int tid = threadIdx.x;
    int wg = blockIdx.x;
    int b = wg >> 9;
    int pair = wg & 511;
    int n0 = pair * 2;
    int y = n0 >> 5;
    int x0 = n0 & 31;

    // ---- phase 0: build activated t0 in LDS: [nl][k][r(pad 68)] ----
    for (int t = tid; t < 2 * KK * 68; t += 128) {
        int r = t % 68;
        int rest = t / 68;
        int k = rest % KK;
        int nl = rest / KK;
        int di = k / 7 - 3, dj = k % 7 - 3;
        int yy = refl(y + di), xx = refl(x0 + nl + dj);
        int n = n0 + nl, nb = yy * 32 + xx;
        float va = 0.f;
        if (r < 64) {
            float v = x1t[(b * HWTOT + n) * REL + r] - x2t[(b * HWTOT + nb) * REL + r];
            va = fmaxf(fmaf(a0[r], v, c0[r]), 0.f);
        } else if (r < 66) {
            float v = pm[n * 2 + (r - 64)] - pm[nb * 2 + (r - 64)];
            va = fmaxf(fmaf(a0[r], v, c0[r]), 0.f);
        }
        ldsA[(nl * KK + k) * 68 + r] = va;
    }
    __syncthreads();

    // ---- phase 1: t1 = relu(bn1(wcw1 @ t0)) -> ldsB[nl][k][co] ----
    {
        int co = tid & 63, nl = tid >> 6;
        float w[68];
#pragma unroll
        for (int r = 0; r < 66; r++) w[r] = wcw1[co * 66 + r];
        w[66] = 0.f; w[67] = 0.f;
        float av = a1[co], cv = c1[co];
        for (int k = 0; k < KK; k++) {
            const float* base = &ldsA[(nl * KK + k) * 68];
            float s0 = 0.f, s1 = 0.f, s2 = 0.f, s3 = 0.f;
#pragma unroll
            for (int rc = 0; rc < 17; rc++) {
                float4 v = *(const float4*)(base + rc * 4);
                s0 += w[rc * 4 + 0] * v.x;
                s1 += w[rc * 4 + 1] * v.y;
                s2 += w[rc * 4 + 2] * v.z;
                s3 += w[rc * 4 + 3] * v.w;
            }
            float acc = (s0 + s1) + (s2 + s3);
            ldsB[(nl * KK + k) * 64 + co] = fmaxf(fmaf(av, acc, cv), 0.f);
        }
    }
    __syncthreads();

    // ---- phase 2: s = wcw2 @ t1 + b; softmax over k; wgt -> ldsB[nl][k][g] ----
    {
        int g = tid & 63, nl = tid >> 6;
        float wv[64];
#pragma unroll
        for (int c = 0; c < 64; c++) wv[c] = wcw2[g * 64 + c];
        float bias = bcw2[g];
        float* sl = &ldsA[(nl * 64 + g) * KK];
        for (int k = 0; k < KK; k++) {
            const float* base = &ldsB[(nl * KK + k) * 64];
            float s0 = bias, s1 = 0.f, s2 = 0.f, s3 = 0.f;
#pragma unroll
            for (int cc = 0; cc < 16; cc++) {
                float4 v = *(const float4*)(base + cc * 4);
                s0 += wv[cc * 4 + 0] * v.x;
                s1 += wv[cc * 4 + 1] * v.y;
                s2 += wv[cc * 4 + 2] * v.z;
                s3 += wv[cc * 4 + 3] * v.w;
            }
            sl[k] = (s0 + s1) + (s2 + s3);
        }
        float mx = -1e30f;
        for (int k = 0; k < KK; k++) mx = fmaxf(mx, sl[k]);
        float sum = 0.f;
        for (int k = 0; k < KK; k++) { float e = expf(sl[k] - mx); sl[k] = e; sum += e; }
        float inv = 1.f / sum;
        __syncthreads();  // all t1 reads complete before overwrite
        for (int k = 0; k < KK; k++) ldsB[(nl * KK + k) * 64 + g] = sl[k] * inv;
    }
    __syncthreads();

    // ---- phase 3: aggregation over 8 chunks of 64 channels ----
    {
        int cl = tid & 63, nl = tid >> 6;
        for (int ch = 0; ch < 8; ch++) {
            int cbase = ch * 64;
#pragma unroll
            for (int i = 0; i < 28; i++) {
                int t = tid + i * 128;
                int rx = t & 7;
                int rest = t >> 3;
                int ry = rest % 7;
                int c = rest / 7;
                int yy = refl(y + ry - 3), xx = refl(x0 + rx - 3);
                ldsA[c * 61 + ry * 8 + rx] = x3[(b * COUT + cbase + c) * HWTOT + yy * 32 + xx];
            }
            __syncthreads();
            int c = cbase + cl;
            int g = c >> 3;
            float acc = 0.f;
#pragma unroll
            for (int k = 0; k < KK; k++) {
                int di = k / 7, dj = k % 7;
                acc += ldsB[(nl * KK + k) * 64 + g] * ldsA[cl * 61 + di * 8 + dj + nl];
            }
            out[(b * COUT + c) * HWTOT + y * 32 + x0 + nl] = acc;
            __syncthreads();
        }
    }
}

extern "C" void kernel_launch(void* const* d_in, const int* in_sizes, int n_in,
                              void* d_out, int out_size, void* d_ws, size_t ws_size,
                              hipStream_t stream) {
    const float* x = (const float*)d_in[0];
    const float* w1 = (const float*)d_in[1];
    const float* b1 = (const float*)d_in[2];
    const float* w2 = (const float*)d_in[3];
    const float* b2 = (const float*)d_in[4];
    const float* w3 = (const float*)d_in[5];
    const float* b3 = (const float*)d_in[6];
    const float* wp = (const float*)d_in[7];
    const float* bp = (const float*)d_in[8];
    const float* g0 = (const float*)d_in[9];
    const float* be0 = (const float*)d_in[10];
    const float* m0 = (const float*)d_in[11];
    const float* v0 = (const float*)d_in[12];
    const float* wcw1 = (const float*)d_in[13];
    const float* g1 = (const float*)d_in[14];
    const float* be1 = (const float*)d_in[15];
    const float* m1 = (const float*)d_in[16];
    const float* v1 = (const float*)d_in[17];
    const float* wcw2 = (const float*)d_in[18];
    const float* bcw2 = (const float*)d_in[19];
    float* ws = (float*)d_ws;
    float* out = (float*)d_out;

    k_setup<<<1, 256, 0, stream>>>(wp, bp, g0, be0, m0, v0, g1, be1, m1, v1, ws);
    k_proj<<<dim3(16, 10, 4), 256, 0, stream>>>(x, w1, b1, w2, b2, w3, b3, ws);
    k_fused<<<2048, 128, 0, stream>>>(wcw1, wcw2, bcw2, ws, out);
}

// Round 3
// 115.602 us; speedup vs baseline: 2.8814x; 2.8814x over previous
//
#include <hip/hip_runtime.h>
#include <math.h>

typedef float f32x4 __attribute__((ext_vector_type(4)));
typedef short s16x8 __attribute__((ext_vector_type(8)));

#define KKW 49
#define HWTOT 1024
#define CIN 512
#define COUT 512

// ws float offsets
#define OFF_X1T 0
#define OFF_X2T 262144
#define OFF_X3T 524288
#define OFF_PM  2621440
#define OFF_A0  2623488
#define OFF_C0  2623554
#define OFF_W64 2623620
#define OFF_W65 2623684
#define OFF_C1V 2623748
#define OFF_W1B 2623812   /* 4096 bf16 (a1-folded wcw1[:, :64]) */
#define OFF_W2B 2625860   /* 4096 bf16 (wcw2) */

// LDS byte offsets
#define T0_OFF  0
#define T1_OFF  16384
#define R3_OFF  32768   /* ph0: x2 slab [56][68] f32 ; ph2+: wgt [2][49][64] f32 swizzled */
#define X1P_OFF 57856
#define T64_OFF 58368
#define T65_OFF 58880
#define NBO_OFF 59392
#define SMEM_BYTES 59904

#define SWZ(bb)  ((bb) ^ ((((bb) >> 7) & 7) << 4))
#define SWZW(bb) ((bb) ^ ((((bb) >> 8) & 7) << 4))

__device__ __forceinline__ int refl(int m) {
    if (m < 0) m = -m;
    if (m > 31) m = 62 - m;
    return m;
}

__device__ __forceinline__ unsigned short fbf(float f) {
    unsigned u = __builtin_bit_cast(unsigned, f);
    unsigned r = u + 0x7fffu + ((u >> 16) & 1u);
    return (unsigned short)(r >> 16);
}

__global__ void k_setup(const float* __restrict__ wp, const float* __restrict__ bp,
                        const float* __restrict__ g0, const float* __restrict__ be0,
                        const float* __restrict__ m0, const float* __restrict__ v0,
                        const float* __restrict__ wcw1,
                        const float* __restrict__ g1, const float* __restrict__ be1,
                        const float* __restrict__ m1, const float* __restrict__ v1,
                        const float* __restrict__ wcw2,
                        float* __restrict__ ws) {
    int tid = threadIdx.x;
    float* pm = ws + OFF_PM;
    for (int n = tid; n < HWTOT; n += 256) {
        int xx = n & 31, yy = n >> 5;
        float lw = -1.f + (2.f / 31.f) * xx;
        float lh = -1.f + (2.f / 31.f) * yy;
        pm[n * 2 + 0] = wp[0] * lw + wp[1] * lh + bp[0];
        pm[n * 2 + 1] = wp[2] * lw + wp[3] * lh + bp[1];
    }
    if (tid < 66) {
        float a = g0[tid] * rsqrtf(v0[tid] + 1e-5f);
        ws[OFF_A0 + tid] = a;
        ws[OFF_C0 + tid] = be0[tid] - m0[tid] * a;
    }
    if (tid < 64) {
        float a1c = g1[tid] * rsqrtf(v1[tid] + 1e-5f);
        ws[OFF_W64 + tid] = a1c * wcw1[tid * 66 + 64];
        ws[OFF_W65 + tid] = a1c * wcw1[tid * 66 + 65];
        ws[OFF_C1V + tid] = be1[tid] - m1[tid] * a1c;
    }
    unsigned short* w1b = (unsigned short*)(ws + OFF_W1B);
    unsigned short* w2b = (unsigned short*)(ws + OFF_W2B);
    for (int t = tid; t < 4096; t += 256) {
        int co = t >> 6, r = t & 63;
        float a1c = g1[co] * rsqrtf(v1[co] + 1e-5f);
        w1b[t] = fbf(a1c * wcw1[co * 66 + r]);
        w2b[t] = fbf(wcw2[t]);
    }
}

// 640x1024x512 GEMM per batch -> x1t' (bn0-scaled, [n][64]), x2t' ([n][64]), x3t ([n][512])
__global__ __launch_bounds__(256) void k_proj(
        const float* __restrict__ x,
        const float* __restrict__ w1, const float* __restrict__ b1,
        const float* __restrict__ w2, const float* __restrict__ b2,
        const float* __restrict__ w3, const float* __restrict__ b3,
        float* __restrict__ ws) {
    __shared__ __align__(16) float As[64 * 17];
    __shared__ __align__(16) float Bs[16 * 64];
    int tid = threadIdx.x;
    int n0 = blockIdx.x * 64;
    int mT = blockIdx.y;
    int b = blockIdx.z;
    int mq = tid >> 4, nq = tid & 15;
    float acc[4][4];
#pragma unroll
    for (int i = 0; i < 4; i++)
#pragma unroll
        for (int j = 0; j < 4; j++) acc[i][j] = 0.f;

    for (int k0 = 0; k0 < CIN; k0 += 16) {
#pragma unroll
        for (int i = 0; i < 4; i++) {
            int t = tid + i * 256;
            int k = t & 15, m = t >> 4;
            int mg = mT * 64 + m;
            const float* Wrow;
            if (mg < 64) Wrow = w1 + mg * CIN;
            else if (mg < 128) Wrow = w2 + (mg - 64) * CIN;
            else Wrow = w3 + (mg - 128) * CIN;
            As[m * 17 + k] = Wrow[k0 + k];
        }
#pragma unroll
        for (int i = 0; i < 4; i++) {
            int t = tid + i * 256;
            int n = t & 63, k = t >> 6;
            Bs[k * 64 + n] = x[(b * CIN + k0 + k) * HWTOT + n0 + n];
        }
        __syncthreads();
#pragma unroll
        for (int k = 0; k < 16; k++) {
            float4 bv = *(const float4*)&Bs[k * 64 + nq * 4];
            float av[4];
#pragma unroll
            for (int i = 0; i < 4; i++) av[i] = As[(mq * 4 + i) * 17 + k];
#pragma unroll
            for (int i = 0; i < 4; i++) {
                acc[i][0] += av[i] * bv.x;
                acc[i][1] += av[i] * bv.y;
                acc[i][2] += av[i] * bv.z;
                acc[i][3] += av[i] * bv.w;
            }
        }
        __syncthreads();
    }
    float* x1t = ws + OFF_X1T;
    float* x2t = ws + OFF_X2T;
    float* x3t = ws + OFF_X3T;
#pragma unroll
    for (int i = 0; i < 4; i++) {
        int mg = mT * 64 + mq * 4 + i;
        if (mg < 64) {
            float bias = b1[mg];
            float aa = ws[OFF_A0 + mg], cc = ws[OFF_C0 + mg];
#pragma unroll
            for (int j = 0; j < 4; j++) {
                int n = n0 + nq * 4 + j;
                x1t[(b * HWTOT + n) * 64 + mg] = aa * (acc[i][j] + bias) + cc;
            }
        } else if (mg < 128) {
            int r = mg - 64;
            float bias = b2[r];
            float aa = ws[OFF_A0 + r];
#pragma unroll
            for (int j = 0; j < 4; j++) {
                int n = n0 + nq * 4 + j;
                x2t[(b * HWTOT + n) * 64 + r] = aa * (acc[i][j] + bias);
            }
        } else {
            float bias = b3[mg - 128];
#pragma unroll
            for (int j = 0; j < 4; j++) {
                int n = n0 + nq * 4 + j;
                x3t[(b * HWTOT + n) * 512 + (mg - 128)] = acc[i][j] + bias;
            }
        }
    }
}

// One WG = (batch, 2 adjacent pixels). 256 threads = 4 waves. MFMA GEMMs.
__global__ __launch_bounds__(256) void k_fused(
        const float* __restrict__ ws, float* __restrict__ out) {
    __shared__ __align__(16) char smem[SMEM_BYTES];

    int tid = threadIdx.x;
    int lane = tid & 63;
    int wv = tid >> 6;
    int lidx = lane & 15;
    int q = lane >> 4;

    int wg = blockIdx.x;
    int b = wg >> 9;
    int n0 = (wg & 511) * 2;
    int y = n0 >> 5, x0 = n0 & 31;

    const float* x1t = ws + OFF_X1T;
    const float* x2t = ws + OFF_X2T;
    const float* x3t = ws + OFF_X3T;
    const float* pm = ws + OFF_PM;

    // ---- ph0a: A-frags + consts + x1p + x2 slab + t64/t65/nbo ----
    const unsigned short* w1b = (const unsigned short*)(ws + OFF_W1B);
    const unsigned short* w2b = (const unsigned short*)(ws + OFF_W2B);
    s16x8 af1[2], af2[2];
#pragma unroll
    for (int ks = 0; ks < 2; ks++) {
        int idx = (wv * 16 + lidx) * 64 + ks * 32 + q * 8;
        af1[ks] = *(const s16x8*)(w1b + idx);
        af2[ks] = *(const s16x8*)(w2b + idx);
    }
    f32x4 w64c = *(const f32x4*)(ws + OFF_W64 + wv * 16 + q * 4);
    f32x4 w65c = *(const f32x4*)(ws + OFF_W65 + wv * 16 + q * 4);
    f32x4 c1c  = *(const f32x4*)(ws + OFF_C1V + wv * 16 + q * 4);

    float* x1p = (float*)(smem + X1P_OFF);
    if (tid < 32) {
        int nl = tid >> 4, rq = tid & 15;
        *(f32x4*)(x1p + nl * 64 + rq * 4) =
            *(const f32x4*)(x1t + (b * HWTOT + n0 + nl) * 64 + rq * 4);
    }
    float* slab = (float*)(smem + R3_OFF);
    for (int t = tid; t < 896; t += 256) {
        int row = t >> 4, rq = t & 15;
        int sy = refl(y + (row >> 3) - 3);
        int sx = refl(x0 + (row & 7) - 3);
        *(f32x4*)(slab + row * 68 + rq * 4) =
            *(const f32x4*)(x2t + (b * HWTOT + sy * 32 + sx) * 64 + rq * 4);
    }
    if (tid < 128) {
        int col = tid, nl = col >> 6, k = col & 63;
        float tv0 = 0.f, tv1 = 0.f;
        int nb = 0;
        if (k < KKW) {
            int di = k / 7 - 3, dj = k % 7 - 3;
            nb = refl(y + di) * 32 + refl(x0 + nl + dj);
            int n = n0 + nl;
            float a064 = ws[OFF_A0 + 64], c064 = ws[OFF_C0 + 64];
            float a065 = ws[OFF_A0 + 65], c065 = ws[OFF_C0 + 65];
            tv0 = fmaxf(fmaf(a064, pm[n * 2 + 0] - pm[nb * 2 + 0], c064), 0.f);
            tv1 = fmaxf(fmaf(a065, pm[n * 2 + 1] - pm[nb * 2 + 1], c065), 0.f);
        }
        ((float*)(smem + T64_OFF))[col] = tv0;
        ((float*)(smem + T65_OFF))[col] = tv1;
        ((int*)(smem + NBO_OFF))[col] = nb;
    }
    __syncthreads();

    // ---- ph0b: t0 bf16 [128 col][64 r] swizzled ----
    {
        int col = tid >> 1, rh = tid & 1;
        int nl = col >> 6, k = col & 63;
        char* t0p = smem + T0_OFF;
        if (k < KKW) {
            int pos = (k / 7) * 8 + nl + (k % 7);
            const float* sr = slab + pos * 68 + rh * 32;
            const float* xr = x1p + nl * 64 + rh * 32;
#pragma unroll
            for (int j = 0; j < 4; j++) {
                f32x4 a0v = *(const f32x4*)(xr + j * 8);
                f32x4 a1v = *(const f32x4*)(xr + j * 8 + 4);
                f32x4 b0v = *(const f32x4*)(sr + j * 8);
                f32x4 b1v = *(const f32x4*)(sr + j * 8 + 4);
                s16x8 h;
#pragma unroll
                for (int i = 0; i < 4; i++) h[i] = (short)fbf(fmaxf(a0v[i] - b0v[i], 0.f));
#pragma unroll
                for (int i = 0; i < 4; i++) h[4 + i] = (short)fbf(fmaxf(a1v[i] - b1v[i], 0.f));
                int byte = col * 128 + (rh * 32 + j * 8) * 2;
                *(s16x8*)(t0p + SWZ(byte)) = h;
            }
        } else {
            s16x8 z = (s16x8)0;
#pragma unroll
            for (int j = 0; j < 4; j++) {
                int byte = col * 128 + (rh * 32 + j * 8) * 2;
                *(s16x8*)(t0p + SWZ(byte)) = z;
            }
        }
    }
    __syncthreads();

    // ---- ph1: GEMM1 (wave wv owns co-tile wv, all 8 col-tiles) ----
    f32x4 acc[8];
#pragma unroll
    for (int ct = 0; ct < 8; ct++) acc[ct] = (f32x4)0.f;
    {
        const char* t0p = smem + T0_OFF;
#pragma unroll
        for (int ct = 0; ct < 8; ct++) {
            int col = ct * 16 + lidx;
            int base = col * 128 + q * 16;
            s16x8 b0 = *(const s16x8*)(t0p + SWZ(base));
            s16x8 b1 = *(const s16x8*)(t0p + SWZ(base + 64));
            acc[ct] = __builtin_amdgcn_mfma_f32_16x16x32_bf16(af1[0], b0, acc[ct], 0, 0, 0);
            acc[ct] = __builtin_amdgcn_mfma_f32_16x16x32_bf16(af1[1], b1, acc[ct], 0, 0, 0);
        }
    }
    // epilogue: t1 = relu(acc + pos + c1) -> bf16 LDS [col][co] swizzled
    {
        char* t1p = smem + T1_OFF;
        const float* t64p = (const float*)(smem + T64_OFF);
        const float* t65p = (const float*)(smem + T65_OFF);
#pragma unroll
        for (int ct = 0; ct < 8; ct++) {
            int col = ct * 16 + lidx;
            float s64 = t64p[col], s65 = t65p[col];
            unsigned short h[4];
#pragma unroll
            for (int r = 0; r < 4; r++) {
                float v = acc[ct][r] + w64c[r] * s64 + w65c[r] * s65 + c1c[r];
                h[r] = fbf(fmaxf(v, 0.f));
            }
            unsigned lo = (unsigned)h[0] | ((unsigned)h[1] << 16);
            unsigned hi = (unsigned)h[2] | ((unsigned)h[3] << 16);
            int byte = col * 128 + (wv * 16 + q * 4) * 2;
            uint2 pk; pk.x = lo; pk.y = hi;
            *(uint2*)(t1p + SWZ(byte)) = pk;
        }
    }
    __syncthreads();

    // ---- ph2: GEMM2 (wave wv owns g-tile wv) + softmax + wgt -> LDS ----
    f32x4 acc2[8];
#pragma unroll
    for (int ct = 0; ct < 8; ct++) acc2[ct] = (f32x4)0.f;
    {
        const char* t1p = smem + T1_OFF;
#pragma unroll
        for (int ct = 0; ct < 8; ct++) {
            int col = ct * 16 + lidx;
            int base = col * 128 + q * 16;
            s16x8 b0 = *(const s16x8*)(t1p + SWZ(base));
            s16x8 b1 = *(const s16x8*)(t1p + SWZ(base + 64));
            acc2[ct] = __builtin_amdgcn_mfma_f32_16x16x32_bf16(af2[0], b0, acc2[ct], 0, 0, 0);
            acc2[ct] = __builtin_amdgcn_mfma_f32_16x16x32_bf16(af2[1], b1, acc2[ct], 0, 0, 0);
        }
    }
    {
        char* wgtp = smem + R3_OFF;
#pragma unroll
        for (int p = 0; p < 2; p++) {
            float m[4] = {-1e30f, -1e30f, -1e30f, -1e30f};
#pragma unroll
            for (int kt = 0; kt < 4; kt++) {
                int k = kt * 16 + lidx;
                if (k < KKW) {
#pragma unroll
                    for (int r = 0; r < 4; r++) m[r] = fmaxf(m[r], acc2[p * 4 + kt][r]);
                }
            }
#pragma unroll
            for (int r = 0; r < 4; r++) {
                m[r] = fmaxf(m[r], __shfl_xor(m[r], 1));
                m[r] = fmaxf(m[r], __shfl_xor(m[r], 2));
                m[r] = fmaxf(m[r], __shfl_xor(m[r], 4));
                m[r] = fmaxf(m[r], __shfl_xor(m[r], 8));
            }
            float s[4] = {0.f, 0.f, 0.f, 0.f};
#pragma unroll
            for (int kt = 0; kt < 4; kt++) {
                int k = kt * 16 + lidx;
#pragma unroll
                for (int r = 0; r < 4; r++) {
                    float e = (k < KKW) ? exp2f((acc2[p * 4 + kt][r] - m[r]) * 1.44269504f) : 0.f;
                    acc2[p * 4 + kt][r] = e;
                    s[r] += e;
                }
            }
#pragma unroll
            for (int r = 0; r < 4; r++) {
                s[r] += __shfl_xor(s[r], 1);
                s[r] += __shfl_xor(s[r], 2);
                s[r] += __shfl_xor(s[r], 4);
                s[r] += __shfl_xor(s[r], 8);
            }
            float inv[4];
#pragma unroll
            for (int r = 0; r < 4; r++) inv[r] = 1.f / s[r];
#pragma unroll
            for (int kt = 0; kt < 4; kt++) {
                int k = kt * 16 + lidx;
                if (k < KKW) {
                    f32x4 v;
#pragma unroll
                    for (int r = 0; r < 4; r++) v[r] = acc2[p * 4 + kt][r] * inv[r];
                    int byte = ((p * KKW + k) * 64 + wv * 16 + q * 4) * 4;
                    *(f32x4*)(wgtp + SWZW(byte)) = v;
                }
            }
        }
    }
    __syncthreads();

    // ---- ph3: aggregation, float4 over channels, direct-global x3t ----
    {
        int c4 = tid & 127, nl = tid >> 7;
        int c = c4 * 4, g = c4 >> 1;
        const int* nbo = (const int*)(smem + NBO_OFF);
        const char* wgtp = smem + R3_OFF;
        f32x4 acc4 = (f32x4)0.f;
        int bbase = b * HWTOT;
#pragma unroll 7
        for (int k = 0; k < KKW; k++) {
            int nb = nbo[nl * 64 + k];
            float w = *(const float*)(wgtp + SWZW(((nl * KKW + k) * 64 + g) * 4));
            f32x4 v = *(const f32x4*)(x3t + (bbase + nb) * 512 + c);
#pragma unroll
            for (int r = 0; r < 4; r++) acc4[r] = fmaf(w, v[r], acc4[r]);
        }
        int n = y * 32 + x0 + nl;
#pragma unroll
        for (int r = 0; r < 4; r++)
            out[(b * COUT + c + r) * HWTOT + n] = acc4[r];
    }
}

extern "C" void kernel_launch(void* const* d_in, const int* in_sizes, int n_in,
                              void* d_out, int out_size, void* d_ws, size_t ws_size,
                              hipStream_t stream) {
    const float* x = (const float*)d_in[0];
    const float* w1 = (const float*)d_in[1];
    const float* b1 = (const float*)d_in[2];
    const float* w2 = (const float*)d_in[3];
    const float* b2 = (const float*)d_in[4];
    const float* w3 = (const float*)d_in[5];
    const float* b3 = (const float*)d_in[6];
    const float* wp = (const float*)d_in[7];
    const float* bp = (const float*)d_in[8];
    const float* g0 = (const float*)d_in[9];
    const float* be0 = (const float*)d_in[10];
    const float* m0 = (const float*)d_in[11];
    const float* v0 = (const float*)d_in[12];
    const float* wcw1 = (const float*)d_in[13];
    const float* g1 = (const float*)d_in[14];
    const float* be1 = (const float*)d_in[15];
    const float* m1 = (const float*)d_in[16];
    const float* v1 = (const float*)d_in[17];
    const float* wcw2 = (const float*)d_in[18];
    float* ws = (float*)d_ws;
    float* out = (float*)d_out;

    k_setup<<<1, 256, 0, stream>>>(wp, bp, g0, be0, m0, v0, wcw1, g1, be1, m1, v1, wcw2, ws);
    k_proj<<<dim3(16, 10, 4), 256, 0, stream>>>(x, w1, b1, w2, b2, w3, b3, ws);
    k_fused<<<2048, 256, 0, stream>>>(ws, out);
}

// Round 4
// 79.371 us; speedup vs baseline: 4.1967x; 1.4565x over previous
//
#include <hip/hip_runtime.h>
#include <math.h>

typedef float f32x4 __attribute__((ext_vector_type(4)));
typedef short s16x8 __attribute__((ext_vector_type(8)));

#define KKW 49
#define HWTOT 1024
#define CIN 512
#define COUT 512

// ws float offsets
#define OFF_X1T 0
#define OFF_X2T 262144
#define OFF_X3T 524288
#define OFF_PM  2621440
#define OFF_A0  2623488
#define OFF_C0  2623554
#define OFF_W64 2623620
#define OFF_W65 2623684
#define OFF_C1V 2623748
#define OFF_W1B 2623812   /* 4096 bf16 (a1-folded wcw1[:, :64]) */
#define OFF_W2B 2625860   /* 4096 bf16 (wcw2) */
#define OFF_WT  2627908   /* 640x512 bf16, 5x8 tiles of [128m][64k] swizzled */
#define OFF_XT  2791748   /* 4x1024x512 bf16, 4x8x8 tiles of [128n][64k] swizzled */
#define WS_NEED_FLOATS 3840324ull

// LDS byte offsets (k_fused)
#define T0_OFF  0
#define T1_OFF  16384
#define R3_OFF  32768   /* ph0: x2 slab [56][68] f32 ; ph2+: wgt [2][49][64] f32 swizzled */
#define X1P_OFF 57856
#define T64_OFF 58368
#define T65_OFF 58880
#define NBO_OFF 59392
#define SMEM_BYTES 59904

#define SWZ(bb)  ((bb) ^ ((((bb) >> 7) & 7) << 4))
#define SWZW(bb) ((bb) ^ ((((bb) >> 8) & 7) << 4))

#define GLD16(g, l) __builtin_amdgcn_global_load_lds( \
    (const __attribute__((address_space(1))) void*)(g), \
    (__attribute__((address_space(3))) void*)(l), 16, 0, 0)

__device__ __forceinline__ int refl(int m) {
    if (m < 0) m = -m;
    if (m > 31) m = 62 - m;
    return m;
}

__device__ __forceinline__ unsigned short fbf(float f) {
    unsigned u = __builtin_bit_cast(unsigned, f);
    unsigned r = u + 0x7fffu + ((u >> 16) & 1u);
    return (unsigned short)(r >> 16);
}

__global__ void k_setup(const float* __restrict__ wp, const float* __restrict__ bp,
                        const float* __restrict__ g0, const float* __restrict__ be0,
                        const float* __restrict__ m0, const float* __restrict__ v0,
                        const float* __restrict__ wcw1,
                        const float* __restrict__ g1, const float* __restrict__ be1,
                        const float* __restrict__ m1, const float* __restrict__ v1,
                        const float* __restrict__ wcw2,
                        float* __restrict__ ws) {
    int tid = threadIdx.x;
    float* pm = ws + OFF_PM;
    for (int n = tid; n < HWTOT; n += 256) {
        int xx = n & 31, yy = n >> 5;
        float lw = -1.f + (2.f / 31.f) * xx;
        float lh = -1.f + (2.f / 31.f) * yy;
        pm[n * 2 + 0] = wp[0] * lw + wp[1] * lh + bp[0];
        pm[n * 2 + 1] = wp[2] * lw + wp[3] * lh + bp[1];
    }
    if (tid < 66) {
        float a = g0[tid] * rsqrtf(v0[tid] + 1e-5f);
        ws[OFF_A0 + tid] = a;
        ws[OFF_C0 + tid] = be0[tid] - m0[tid] * a;
    }
    if (tid < 64) {
        float a1c = g1[tid] * rsqrtf(v1[tid] + 1e-5f);
        ws[OFF_W64 + tid] = a1c * wcw1[tid * 66 + 64];
        ws[OFF_W65 + tid] = a1c * wcw1[tid * 66 + 65];
        ws[OFF_C1V + tid] = be1[tid] - m1[tid] * a1c;
    }
    unsigned short* w1b = (unsigned short*)(ws + OFF_W1B);
    unsigned short* w2b = (unsigned short*)(ws + OFF_W2B);
    for (int t = tid; t < 4096; t += 256) {
        int co = t >> 6, r = t & 63;
        float a1c = g1[co] * rsqrtf(v1[co] + 1e-5f);
        w1b[t] = fbf(a1c * wcw1[co * 66 + r]);
        w2b[t] = fbf(wcw2[t]);
    }
}

// Pack weights (blocks 0..39) and x-transpose (blocks 40..295) into swizzled bf16 tiles.
__global__ __launch_bounds__(256) void k_prep(
        const float* __restrict__ x,
        const float* __restrict__ w1, const float* __restrict__ w2,
        const float* __restrict__ w3, float* __restrict__ ws) {
    int bid = blockIdx.x;
    int tid = threadIdx.x;
    if (bid < 40) {
        int mT = bid / 8, kT = bid % 8;
        char* dst = (char*)(ws + OFF_WT) + (mT * 8 + kT) * 16384;
#pragma unroll
        for (int it = 0; it < 4; ++it) {
            int item = it * 256 + tid;
            int m = item >> 3, k8 = item & 7;
            int mg = mT * 128 + m;
            const float* src;
            if (mg < 64) src = w1 + mg * CIN;
            else if (mg < 128) src = w2 + (mg - 64) * CIN;
            else src = w3 + (mg - 128) * CIN;
            int k0 = kT * 64 + k8 * 8;
            s16x8 h;
#pragma unroll
            for (int i = 0; i < 8; i++) h[i] = (short)fbf(src[k0 + i]);
            *(s16x8*)(dst + SWZ(m * 128 + k8 * 16)) = h;
        }
    } else {
        __shared__ float lds[64 * 129];
        int t = bid - 40;  // b(4) nT(8) kT(8)
        int b = t >> 6, nT = (t >> 3) & 7, kT = t & 7;
        const float* src = x + (b * CIN + kT * 64) * HWTOT + nT * 128;
#pragma unroll
        for (int it = 0; it < 8; ++it) {
            int item = it * 256 + tid;  // 2048 float4: kk(64) x n4(32)
            int kk = item >> 5, n4 = item & 31;
            float4 v = *(const float4*)(src + kk * HWTOT + n4 * 4);
            float* d = &lds[kk * 129 + n4 * 4];
            d[0] = v.x; d[1] = v.y; d[2] = v.z; d[3] = v.w;
        }
        __syncthreads();
        char* dst = (char*)(ws + OFF_XT) + ((b * 8 + nT) * 8 + kT) * 16384;
#pragma unroll
        for (int it = 0; it < 4; ++it) {
            int item = it * 256 + tid;  // n(128) x k8(8)
            int n = item >> 3, k8 = item & 7;
            s16x8 h;
#pragma unroll
            for (int i = 0; i < 8; i++) h[i] = (short)fbf(lds[(k8 * 8 + i) * 129 + n]);
            *(s16x8*)(dst + SWZ(n * 128 + k8 * 16)) = h;
        }
    }
}

// MFMA projection GEMM: C[640 x 1024] = W x X per batch. 128x128 tile, BK=64, dbuf LDS.
__global__ __launch_bounds__(256) void k_projm(
        const float* __restrict__ b1, const float* __restrict__ b2,
        const float* __restrict__ b3, float* __restrict__ ws) {
    __shared__ __align__(16) char smem[65536];
    int tid = threadIdx.x, lane = tid & 63, wv = tid >> 6;
    int lidx = lane & 15, q = lane >> 4;
    int mT = blockIdx.x, nT = blockIdx.y, b = blockIdx.z;
    int mh = wv >> 1, nh = wv & 1;
    const char* wtg = (const char*)(ws + OFF_WT) + mT * 8 * 16384;
    const char* xtg = (const char*)(ws + OFF_XT) + (b * 8 + nT) * 8 * 16384;

    f32x4 acc[4][4];
#pragma unroll
    for (int i = 0; i < 4; i++)
#pragma unroll
        for (int j = 0; j < 4; j++) acc[i][j] = (f32x4)0.f;

#define STAGE(kt, buf) do { \
        const char* ga_ = wtg + (kt) * 16384; \
        const char* gb_ = xtg + (kt) * 16384; \
        char* la_ = smem + (buf) * 32768; \
        char* lb_ = la_ + 16384; \
        _Pragma("unroll") \
        for (int c_ = 0; c_ < 4; c_++) { \
            GLD16(ga_ + c_ * 4096 + wv * 1024 + lane * 16, la_ + c_ * 4096 + wv * 1024); \
            GLD16(gb_ + c_ * 4096 + wv * 1024 + lane * 16, lb_ + c_ * 4096 + wv * 1024); \
        } \
    } while (0)

    STAGE(0, 0);
    __syncthreads();
    for (int kt = 0; kt < 8; kt++) {
        if (kt < 7) STAGE(kt + 1, (kt + 1) & 1);
        const char* la = smem + (kt & 1) * 32768;
        const char* lb = la + 16384;
#pragma unroll
        for (int ks = 0; ks < 2; ks++) {
            s16x8 af[4], bf[4];
            int kb = ks * 64 + q * 16;
#pragma unroll
            for (int f = 0; f < 4; f++) {
                int arow = mh * 64 + f * 16 + lidx;
                int brow = nh * 64 + f * 16 + lidx;
                af[f] = *(const s16x8*)(la + SWZ(arow * 128 + kb));
                bf[f] = *(const s16x8*)(lb + SWZ(brow * 128 + kb));
            }
#pragma unroll
            for (int mf = 0; mf < 4; mf++)
#pragma unroll
                for (int nf = 0; nf < 4; nf++)
                    acc[mf][nf] = __builtin_amdgcn_mfma_f32_16x16x32_bf16(
                        af[mf], bf[nf], acc[mf][nf], 0, 0, 0);
        }
        __syncthreads();
    }
#undef STAGE

    float* x1t = ws + OFF_X1T;
    float* x2t = ws + OFF_X2T;
    float* x3t = ws + OFF_X3T;
#pragma unroll
    for (int mf = 0; mf < 4; mf++) {
        int mloc = mh * 64 + mf * 16 + q * 4;
        int mg = mT * 128 + mloc;
#pragma unroll
        for (int nf = 0; nf < 4; nf++) {
            int n = nT * 128 + nh * 64 + nf * 16 + lidx;
            f32x4 o;
            if (mg < 64) {
#pragma unroll
                for (int r = 0; r < 4; r++)
                    o[r] = ws[OFF_A0 + mg + r] * (acc[mf][nf][r] + b1[mg + r]) + ws[OFF_C0 + mg + r];
                *(f32x4*)(x1t + (b * HWTOT + n) * 64 + mg) = o;
            } else if (mg < 128) {
                int c = mg - 64;
#pragma unroll
                for (int r = 0; r < 4; r++)
                    o[r] = ws[OFF_A0 + c + r] * (acc[mf][nf][r] + b2[c + r]);
                *(f32x4*)(x2t + (b * HWTOT + n) * 64 + c) = o;
            } else {
                int c = mg - 128;
#pragma unroll
                for (int r = 0; r < 4; r++)
                    o[r] = acc[mf][nf][r] + b3[c + r];
                *(f32x4*)(x3t + (b * HWTOT + n) * 512 + c) = o;
            }
        }
    }
}

// Fallback fp32 projection (used only if ws_size is too small for tiles).
__global__ __launch_bounds__(256) void k_proj(
        const float* __restrict__ x,
        const float* __restrict__ w1, const float* __restrict__ b1,
        const float* __restrict__ w2, const float* __restrict__ b2,
        const float* __restrict__ w3, const float* __restrict__ b3,
        float* __restrict__ ws) {
    __shared__ __align__(16) float As[64 * 17];
    __shared__ __align__(16) float Bs[16 * 64];
    int tid = threadIdx.x;
    int n0 = blockIdx.x * 64;
    int mT = blockIdx.y;
    int b = blockIdx.z;
    int mq = tid >> 4, nq = tid & 15;
    float acc[4][4];
#pragma unroll
    for (int i = 0; i < 4; i++)
#pragma unroll
        for (int j = 0; j < 4; j++) acc[i][j] = 0.f;

    for (int k0 = 0; k0 < CIN; k0 += 16) {
#pragma unroll
        for (int i = 0; i < 4; i++) {
            int t = tid + i * 256;
            int k = t & 15, m = t >> 4;
            int mg = mT * 64 + m;
            const float* Wrow;
            if (mg < 64) Wrow = w1 + mg * CIN;
            else if (mg < 128) Wrow = w2 + (mg - 64) * CIN;
            else Wrow = w3 + (mg - 128) * CIN;
            As[m * 17 + k] = Wrow[k0 + k];
        }
#pragma unroll
        for (int i = 0; i < 4; i++) {
            int t = tid + i * 256;
            int n = t & 63, k = t >> 6;
            Bs[k * 64 + n] = x[(b * CIN + k0 + k) * HWTOT + n0 + n];
        }
        __syncthreads();
#pragma unroll
        for (int k = 0; k < 16; k++) {
            float4 bv = *(const float4*)&Bs[k * 64 + nq * 4];
            float av[4];
#pragma unroll
            for (int i = 0; i < 4; i++) av[i] = As[(mq * 4 + i) * 17 + k];
#pragma unroll
            for (int i = 0; i < 4; i++) {
                acc[i][0] += av[i] * bv.x;
                acc[i][1] += av[i] * bv.y;
                acc[i][2] += av[i] * bv.z;
                acc[i][3] += av[i] * bv.w;
            }
        }
        __syncthreads();
    }
    float* x1t = ws + OFF_X1T;
    float* x2t = ws + OFF_X2T;
    float* x3t = ws + OFF_X3T;
#pragma unroll
    for (int i = 0; i < 4; i++) {
        int mg = mT * 64 + mq * 4 + i;
        if (mg < 64) {
            float bias = b1[mg];
            float aa = ws[OFF_A0 + mg], cc = ws[OFF_C0 + mg];
#pragma unroll
            for (int j = 0; j < 4; j++) {
                int n = n0 + nq * 4 + j;
                x1t[(b * HWTOT + n) * 64 + mg] = aa * (acc[i][j] + bias) + cc;
            }
        } else if (mg < 128) {
            int r = mg - 64;
            float bias = b2[r];
            float aa = ws[OFF_A0 + r];
#pragma unroll
            for (int j = 0; j < 4; j++) {
                int n = n0 + nq * 4 + j;
                x2t[(b * HWTOT + n) * 64 + r] = aa * (acc[i][j] + bias);
            }
        } else {
            float bias = b3[mg - 128];
#pragma unroll
            for (int j = 0; j < 4; j++) {
                int n = n0 + nq * 4 + j;
                x3t[(b * HWTOT + n) * 512 + (mg - 128)] = acc[i][j] + bias;
            }
        }
    }
}

// One WG = (batch, 2 adjacent pixels). 256 threads = 4 waves. MFMA GEMMs.
__global__ __launch_bounds__(256) void k_fused(
        const float* __restrict__ ws, float* __restrict__ out) {
    __shared__ __align__(16) char smem[SMEM_BYTES];

    int tid = threadIdx.x;
    int lane = tid & 63;
    int wv = tid >> 6;
    int lidx = lane & 15;
    int q = lane >> 4;

    int wg = blockIdx.x;
    int b = wg >> 9;
    int n0 = (wg & 511) * 2;
    int y = n0 >> 5, x0 = n0 & 31;

    const float* x1t = ws + OFF_X1T;
    const float* x2t = ws + OFF_X2T;
    const float* x3t = ws + OFF_X3T;
    const float* pm = ws + OFF_PM;

    // ---- ph0a: A-frags + consts + x1p + x2 slab + t64/t65/nbo ----
    const unsigned short* w1b = (const unsigned short*)(ws + OFF_W1B);
    const unsigned short* w2b = (const unsigned short*)(ws + OFF_W2B);
    s16x8 af1[2], af2[2];
#pragma unroll
    for (int ks = 0; ks < 2; ks++) {
        int idx = (wv * 16 + lidx) * 64 + ks * 32 + q * 8;
        af1[ks] = *(const s16x8*)(w1b + idx);
        af2[ks] = *(const s16x8*)(w2b + idx);
    }
    f32x4 w64c = *(const f32x4*)(ws + OFF_W64 + wv * 16 + q * 4);
    f32x4 w65c = *(const f32x4*)(ws + OFF_W65 + wv * 16 + q * 4);
    f32x4 c1c  = *(const f32x4*)(ws + OFF_C1V + wv * 16 + q * 4);

    float* x1p = (float*)(smem + X1P_OFF);
    if (tid < 32) {
        int nl = tid >> 4, rq = tid & 15;
        *(f32x4*)(x1p + nl * 64 + rq * 4) =
            *(const f32x4*)(x1t + (b * HWTOT + n0 + nl) * 64 + rq * 4);
    }
    float* slab = (float*)(smem + R3_OFF);
    for (int t = tid; t < 896; t += 256) {
        int row = t >> 4, rq = t & 15;
        int sy = refl(y + (row >> 3) - 3);
        int sx = refl(x0 + (row & 7) - 3);
        *(f32x4*)(slab + row * 68 + rq * 4) =
            *(const f32x4*)(x2t + (b * HWTOT + sy * 32 + sx) * 64 + rq * 4);
    }
    if (tid < 128) {
        int col = tid, nl = col >> 6, k = col & 63;
        float tv0 = 0.f, tv1 = 0.f;
        int nb = 0;
        if (k < KKW) {
            int di = k / 7 - 3, dj = k % 7 - 3;
            nb = refl(y + di) * 32 + refl(x0 + nl + dj);
            int n = n0 + nl;
            float a064 = ws[OFF_A0 + 64], c064 = ws[OFF_C0 + 64];
            float a065 = ws[OFF_A0 + 65], c065 = ws[OFF_C0 + 65];
            tv0 = fmaxf(fmaf(a064, pm[n * 2 + 0] - pm[nb * 2 + 0], c064), 0.f);
            tv1 = fmaxf(fmaf(a065, pm[n * 2 + 1] - pm[nb * 2 + 1], c065), 0.f);
        }
        ((float*)(smem + T64_OFF))[col] = tv0;
        ((float*)(smem + T65_OFF))[col] = tv1;
        ((int*)(smem + NBO_OFF))[col] = nb;
    }
    __syncthreads();

    // ---- ph0b: t0 bf16 [128 col][64 r] swizzled ----
    {
        int col = tid >> 1, rh = tid & 1;
        int nl = col >> 6, k = col & 63;
        char* t0p = smem + T0_OFF;
        if (k < KKW) {
            int pos = (k / 7) * 8 + nl + (k % 7);
            const float* sr = slab + pos * 68 + rh * 32;
            const float* xr = x1p + nl * 64 + rh * 32;
#pragma unroll
            for (int j = 0; j < 4; j++) {
                f32x4 a0v = *(const f32x4*)(xr + j * 8);
                f32x4 a1v = *(const f32x4*)(xr + j * 8 + 4);
                f32x4 b0v = *(const f32x4*)(sr + j * 8);
                f32x4 b1v = *(const f32x4*)(sr + j * 8 + 4);
                s16x8 h;
#pragma unroll
                for (int i = 0; i < 4; i++) h[i] = (short)fbf(fmaxf(a0v[i] - b0v[i], 0.f));
#pragma unroll
                for (int i = 0; i < 4; i++) h[4 + i] = (short)fbf(fmaxf(a1v[i] - b1v[i], 0.f));
                int byte = col * 128 + (rh * 32 + j * 8) * 2;
                *(s16x8*)(t0p + SWZ(byte)) = h;
            }
        } else {
            s16x8 z = (s16x8)0;
#pragma unroll
            for (int j = 0; j < 4; j++) {
                int byte = col * 128 + (rh * 32 + j * 8) * 2;
                *(s16x8*)(t0p + SWZ(byte)) = z;
            }
        }
    }
    __syncthreads();

    // ---- ph1: GEMM1 (wave wv owns co-tile wv, all 8 col-tiles) ----
    f32x4 acc[8];
#pragma unroll
    for (int ct = 0; ct < 8; ct++) acc[ct] = (f32x4)0.f;
    {
        const char* t0p = smem + T0_OFF;
#pragma unroll
        for (int ct = 0; ct < 8; ct++) {
            int col = ct * 16 + lidx;
            int base = col * 128 + q * 16;
            s16x8 b0 = *(const s16x8*)(t0p + SWZ(base));
            s16x8 b1 = *(const s16x8*)(t0p + SWZ(base + 64));
            acc[ct] = __builtin_amdgcn_mfma_f32_16x16x32_bf16(af1[0], b0, acc[ct], 0, 0, 0);
            acc[ct] = __builtin_amdgcn_mfma_f32_16x16x32_bf16(af1[1], b1, acc[ct], 0, 0, 0);
        }
    }
    // epilogue: t1 = relu(acc + pos + c1) -> bf16 LDS [col][co] swizzled
    {
        char* t1p = smem + T1_OFF;
        const float* t64p = (const float*)(smem + T64_OFF);
        const float* t65p = (const float*)(smem + T65_OFF);
#pragma unroll
        for (int ct = 0; ct < 8; ct++) {
            int col = ct * 16 + lidx;
            float s64 = t64p[col], s65 = t65p[col];
            unsigned short h[4];
#pragma unroll
            for (int r = 0; r < 4; r++) {
                float v = acc[ct][r] + w64c[r] * s64 + w65c[r] * s65 + c1c[r];
                h[r] = fbf(fmaxf(v, 0.f));
            }
            unsigned lo = (unsigned)h[0] | ((unsigned)h[1] << 16);
            unsigned hi = (unsigned)h[2] | ((unsigned)h[3] << 16);
            int byte = col * 128 + (wv * 16 + q * 4) * 2;
            uint2 pk; pk.x = lo; pk.y = hi;
            *(uint2*)(t1p + SWZ(byte)) = pk;
        }
    }
    __syncthreads();

    // ---- ph2: GEMM2 (wave wv owns g-tile wv) + softmax + wgt -> LDS ----
    f32x4 acc2[8];
#pragma unroll
    for (int ct = 0; ct < 8; ct++) acc2[ct] = (f32x4)0.f;
    {
        const char* t1p = smem + T1_OFF;
#pragma unroll
        for (int ct = 0; ct < 8; ct++) {
            int col = ct * 16 + lidx;
            int base = col * 128 + q * 16;
            s16x8 b0 = *(const s16x8*)(t1p + SWZ(base));
            s16x8 b1 = *(const s16x8*)(t1p + SWZ(base + 64));
            acc2[ct] = __builtin_amdgcn_mfma_f32_16x16x32_bf16(af2[0], b0, acc2[ct], 0, 0, 0);
            acc2[ct] = __builtin_amdgcn_mfma_f32_16x16x32_bf16(af2[1], b1, acc2[ct], 0, 0, 0);
        }
    }
    {
        char* wgtp = smem + R3_OFF;
#pragma unroll
        for (int p = 0; p < 2; p++) {
            float m[4] = {-1e30f, -1e30f, -1e30f, -1e30f};
#pragma unroll
            for (int kt = 0; kt < 4; kt++) {
                int k = kt * 16 + lidx;
                if (k < KKW) {
#pragma unroll
                    for (int r = 0; r < 4; r++) m[r] = fmaxf(m[r], acc2[p * 4 + kt][r]);
                }
            }
#pragma unroll
            for (int r = 0; r < 4; r++) {
                m[r] = fmaxf(m[r], __shfl_xor(m[r], 1));
                m[r] = fmaxf(m[r], __shfl_xor(m[r], 2));
                m[r] = fmaxf(m[r], __shfl_xor(m[r], 4));
                m[r] = fmaxf(m[r], __shfl_xor(m[r], 8));
            }
            float s[4] = {0.f, 0.f, 0.f, 0.f};
#pragma unroll
            for (int kt = 0; kt < 4; kt++) {
                int k = kt * 16 + lidx;
#pragma unroll
                for (int r = 0; r < 4; r++) {
                    float e = (k < KKW) ? exp2f((acc2[p * 4 + kt][r] - m[r]) * 1.44269504f) : 0.f;
                    acc2[p * 4 + kt][r] = e;
                    s[r] += e;
                }
            }
#pragma unroll
            for (int r = 0; r < 4; r++) {
                s[r] += __shfl_xor(s[r], 1);
                s[r] += __shfl_xor(s[r], 2);
                s[r] += __shfl_xor(s[r], 4);
                s[r] += __shfl_xor(s[r], 8);
            }
            float inv[4];
#pragma unroll
            for (int r = 0; r < 4; r++) inv[r] = 1.f / s[r];
#pragma unroll
            for (int kt = 0; kt < 4; kt++) {
                int k = kt * 16 + lidx;
                if (k < KKW) {
                    f32x4 v;
#pragma unroll
                    for (int r = 0; r < 4; r++) v[r] = acc2[p * 4 + kt][r] * inv[r];
                    int byte = ((p * KKW + k) * 64 + wv * 16 + q * 4) * 4;
                    *(f32x4*)(wgtp + SWZW(byte)) = v;
                }
            }
        }
    }
    __syncthreads();

    // ---- ph3: aggregation, float4 over channels, direct-global x3t ----
    {
        int c4 = tid & 127, nl = tid >> 7;
        int c = c4 * 4, g = c4 >> 1;
        const int* nbo = (const int*)(smem + NBO_OFF);
        const char* wgtp = smem + R3_OFF;
        f32x4 acc4 = (f32x4)0.f;
        int bbase = b * HWTOT;
#pragma unroll 7
        for (int k = 0; k < KKW; k++) {
            int nb = nbo[nl * 64 + k];
            float w = *(const float*)(wgtp + SWZW(((nl * KKW + k) * 64 + g) * 4));
            f32x4 v = *(const f32x4*)(x3t + (bbase + nb) * 512 + c);
#pragma unroll
            for (int r = 0; r < 4; r++) acc4[r] = fmaf(w, v[r], acc4[r]);
        }
        int n = y * 32 + x0 + nl;
#pragma unroll
        for (int r = 0; r < 4; r++)
            out[(b * COUT + c + r) * HWTOT + n] = acc4[r];
    }
}

extern "C" void kernel_launch(void* const* d_in, const int* in_sizes, int n_in,
                              void* d_out, int out_size, void* d_ws, size_t ws_size,
                              hipStream_t stream) {
    const float* x = (const float*)d_in[0];
    const float* w1 = (const float*)d_in[1];
    const float* b1 = (const float*)d_in[2];
    const float* w2 = (const float*)d_in[3];
    const float* b2 = (const float*)d_in[4];
    const float* w3 = (const float*)d_in[5];
    const float* b3 = (const float*)d_in[6];
    const float* wp = (const float*)d_in[7];
    const float* bp = (const float*)d_in[8];
    const float* g0 = (const float*)d_in[9];
    const float* be0 = (const float*)d_in[10];
    const float* m0 = (const float*)d_in[11];
    const float* v0 = (const float*)d_in[12];
    const float* wcw1 = (const float*)d_in[13];
    const float* g1 = (const float*)d_in[14];
    const float* be1 = (const float*)d_in[15];
    const float* m1 = (const float*)d_in[16];
    const float* v1 = (const float*)d_in[17];
    const float* wcw2 = (const float*)d_in[18];
    float* ws = (float*)d_ws;
    float* out = (float*)d_out;

    k_setup<<<1, 256, 0, stream>>>(wp, bp, g0, be0, m0, v0, wcw1, g1, be1, m1, v1, wcw2, ws);
    if (ws_size >= WS_NEED_FLOATS * 4ull) {
        k_prep<<<296, 256, 0, stream>>>(x, w1, w2, w3, ws);
        k_projm<<<dim3(5, 8, 4), 256, 0, stream>>>(b1, b2, b3, ws);
    } else {
        k_proj<<<dim3(16, 10, 4), 256, 0, stream>>>(x, w1, b1, w2, b2, w3, b3, ws);
    }
    k_fused<<<2048, 256, 0, stream>>>(ws, out);
}

// Round 5
// 73.880 us; speedup vs baseline: 4.5086x; 1.0743x over previous
//
#include <hip/hip_runtime.h>
#include <hip/hip_bf16.h>
#include <math.h>

typedef float f32x4 __attribute__((ext_vector_type(4)));
typedef short s16x8 __attribute__((ext_vector_type(8)));

#define KKW 49
#define HWTOT 1024
#define CIN 512
#define COUT 512

// ws float offsets
#define OFF_X1T 0
#define OFF_X2T 262144
#define OFF_X3T 524288
#define OFF_PM  2621440
#define OFF_A0  2623488
#define OFF_C0  2623554
#define OFF_W64 2623620
#define OFF_W65 2623684
#define OFF_C1V 2623748
#define OFF_W1B 2623812   /* 4096 bf16 (a1-folded wcw1[:, :64]) */
#define OFF_W2B 2625860   /* 4096 bf16 (wcw2) - legacy */
#define OFF_W2F 2627908   /* 4096 bf16 (wcw2^T pre-fragmented for GEMM2 B) */
#define OFF_WT  2629956   /* 640x512 bf16, 5x8 tiles of [128m][64k] swizzled */
#define OFF_XT  2793796   /* 4x1024x512 bf16, 4x8x8 tiles of [128n][64k] swizzled */
#define WS_NEED_FLOATS 3842372ull

#define SWZ(bb)  ((bb) ^ ((((bb) >> 7) & 7) << 4))

#define GLD16(g, l) __builtin_amdgcn_global_load_lds( \
    (const __attribute__((address_space(1))) void*)(g), \
    (__attribute__((address_space(3))) void*)(l), 16, 0, 0)

__device__ __forceinline__ int refl(int m) {
    if (m < 0) m = -m;
    if (m > 31) m = 62 - m;
    return m;
}

__device__ __forceinline__ unsigned short fbf(float f) {
    unsigned u = __builtin_bit_cast(unsigned, f);
    unsigned r = u + 0x7fffu + ((u >> 16) & 1u);
    return (unsigned short)(r >> 16);
}

__device__ __forceinline__ unsigned pk2bf(float a, float b) {
    float2 f2; f2.x = a; f2.y = b;
    __hip_bfloat162 h = __float22bfloat162_rn(f2);
    union { __hip_bfloat162 h2; unsigned u; } cv;
    cv.h2 = h;
    return cv.u;
}

__device__ __forceinline__ float bf2f(unsigned short u) {
    unsigned v = (unsigned)u << 16;
    return __builtin_bit_cast(float, v);
}

__global__ void k_setup(const float* __restrict__ wp, const float* __restrict__ bp,
                        const float* __restrict__ g0, const float* __restrict__ be0,
                        const float* __restrict__ m0, const float* __restrict__ v0,
                        const float* __restrict__ wcw1,
                        const float* __restrict__ g1, const float* __restrict__ be1,
                        const float* __restrict__ m1, const float* __restrict__ v1,
                        const float* __restrict__ wcw2,
                        float* __restrict__ ws) {
    int tid = threadIdx.x;
    float* pm = ws + OFF_PM;
    for (int n = tid; n < HWTOT; n += 256) {
        int xx = n & 31, yy = n >> 5;
        float lw = -1.f + (2.f / 31.f) * xx;
        float lh = -1.f + (2.f / 31.f) * yy;
        pm[n * 2 + 0] = wp[0] * lw + wp[1] * lh + bp[0];
        pm[n * 2 + 1] = wp[2] * lw + wp[3] * lh + bp[1];
    }
    if (tid < 66) {
        float a = g0[tid] * rsqrtf(v0[tid] + 1e-5f);
        ws[OFF_A0 + tid] = a;
        ws[OFF_C0 + tid] = be0[tid] - m0[tid] * a;
    }
    if (tid < 64) {
        float a1c = g1[tid] * rsqrtf(v1[tid] + 1e-5f);
        ws[OFF_W64 + tid] = a1c * wcw1[tid * 66 + 64];
        ws[OFF_W65 + tid] = a1c * wcw1[tid * 66 + 65];
        ws[OFF_C1V + tid] = be1[tid] - m1[tid] * a1c;
    }
    unsigned short* w1b = (unsigned short*)(ws + OFF_W1B);
    unsigned short* w2b = (unsigned short*)(ws + OFF_W2B);
    unsigned short* w2f = (unsigned short*)(ws + OFF_W2F);
    for (int t = tid; t < 4096; t += 256) {
        int co = t >> 6, r = t & 63;
        float a1c = g1[co] * rsqrtf(v1[co] + 1e-5f);
        w1b[t] = fbf(a1c * wcw1[co * 66 + r]);
        w2b[t] = fbf(wcw2[t]);
        // pre-fragmented wcw2^T for GEMM2 B-operand: frag ft=(gt*2+ks2), lane l, elem j
        int j = t & 7, idx = t >> 3;
        int ft = idx >> 6, l = idx & 63;
        int gt = ft >> 1, ks2 = ft & 1;
        int g = (l & 15) + gt * 16;
        int c2 = ks2 * 32 + (l >> 4) * 8 + j;
        w2f[t] = fbf(wcw2[g * 64 + c2]);
    }
}

// Pack weights (blocks 0..39) and x-transpose (blocks 40..295) into swizzled bf16 tiles.
__global__ __launch_bounds__(256) void k_prep(
        const float* __restrict__ x,
        const float* __restrict__ w1, const float* __restrict__ w2,
        const float* __restrict__ w3, float* __restrict__ ws) {
    int bid = blockIdx.x;
    int tid = threadIdx.x;
    if (bid < 40) {
        int mT = bid / 8, kT = bid % 8;
        char* dst = (char*)(ws + OFF_WT) + (mT * 8 + kT) * 16384;
#pragma unroll
        for (int it = 0; it < 4; ++it) {
            int item = it * 256 + tid;
            int m = item >> 3, k8 = item & 7;
            int mg = mT * 128 + m;
            const float* src;
            if (mg < 64) src = w1 + mg * CIN;
            else if (mg < 128) src = w2 + (mg - 64) * CIN;
            else src = w3 + (mg - 128) * CIN;
            int k0 = kT * 64 + k8 * 8;
            s16x8 h;
#pragma unroll
            for (int i = 0; i < 8; i++) h[i] = (short)fbf(src[k0 + i]);
            *(s16x8*)(dst + SWZ(m * 128 + k8 * 16)) = h;
        }
    } else {
        __shared__ float lds[64 * 129];
        int t = bid - 40;  // b(4) nT(8) kT(8)
        int b = t >> 6, nT = (t >> 3) & 7, kT = t & 7;
        const float* src = x + (b * CIN + kT * 64) * HWTOT + nT * 128;
#pragma unroll
        for (int it = 0; it < 8; ++it) {
            int item = it * 256 + tid;
            int kk = item >> 5, n4 = item & 31;
            float4 v = *(const float4*)(src + kk * HWTOT + n4 * 4);
            float* d = &lds[kk * 129 + n4 * 4];
            d[0] = v.x; d[1] = v.y; d[2] = v.z; d[3] = v.w;
        }
        __syncthreads();
        char* dst = (char*)(ws + OFF_XT) + ((b * 8 + nT) * 8 + kT) * 16384;
#pragma unroll
        for (int it = 0; it < 4; ++it) {
            int item = it * 256 + tid;
            int n = item >> 3, k8 = item & 7;
            s16x8 h;
#pragma unroll
            for (int i = 0; i < 8; i++) h[i] = (short)fbf(lds[(k8 * 8 + i) * 129 + n]);
            *(s16x8*)(dst + SWZ(n * 128 + k8 * 16)) = h;
        }
    }
}

// MFMA projection GEMM: C[640 x 1024] = W x X per batch. 128x128 tile, BK=64, dbuf LDS.
__global__ __launch_bounds__(256) void k_projm(
        const float* __restrict__ b1, const float* __restrict__ b2,
        const float* __restrict__ b3, float* __restrict__ ws) {
    __shared__ __align__(16) char smem[65536];
    int tid = threadIdx.x, lane = tid & 63, wv = tid >> 6;
    int lidx = lane & 15, q = lane >> 4;
    int mT = blockIdx.x, nT = blockIdx.y, b = blockIdx.z;
    int mh = wv >> 1, nh = wv & 1;
    const char* wtg = (const char*)(ws + OFF_WT) + mT * 8 * 16384;
    const char* xtg = (const char*)(ws + OFF_XT) + (b * 8 + nT) * 8 * 16384;

    f32x4 acc[4][4];
#pragma unroll
    for (int i = 0; i < 4; i++)
#pragma unroll
        for (int j = 0; j < 4; j++) acc[i][j] = (f32x4)0.f;

#define STAGE(kt, buf) do { \
        const char* ga_ = wtg + (kt) * 16384; \
        const char* gb_ = xtg + (kt) * 16384; \
        char* la_ = smem + (buf) * 32768; \
        char* lb_ = la_ + 16384; \
        _Pragma("unroll") \
        for (int c_ = 0; c_ < 4; c_++) { \
            GLD16(ga_ + c_ * 4096 + wv * 1024 + lane * 16, la_ + c_ * 4096 + wv * 1024); \
            GLD16(gb_ + c_ * 4096 + wv * 1024 + lane * 16, lb_ + c_ * 4096 + wv * 1024); \
        } \
    } while (0)

    STAGE(0, 0);
    __syncthreads();
    for (int kt = 0; kt < 8; kt++) {
        if (kt < 7) STAGE(kt + 1, (kt + 1) & 1);
        const char* la = smem + (kt & 1) * 32768;
        const char* lb = la + 16384;
#pragma unroll
        for (int ks = 0; ks < 2; ks++) {
            s16x8 af[4], bf[4];
            int kb = ks * 64 + q * 16;
#pragma unroll
            for (int f = 0; f < 4; f++) {
                int arow = mh * 64 + f * 16 + lidx;
                int brow = nh * 64 + f * 16 + lidx;
                af[f] = *(const s16x8*)(la + SWZ(arow * 128 + kb));
                bf[f] = *(const s16x8*)(lb + SWZ(brow * 128 + kb));
            }
#pragma unroll
            for (int mf = 0; mf < 4; mf++)
#pragma unroll
                for (int nf = 0; nf < 4; nf++)
                    acc[mf][nf] = __builtin_amdgcn_mfma_f32_16x16x32_bf16(
                        af[mf], bf[nf], acc[mf][nf], 0, 0, 0);
        }
        __syncthreads();
    }
#undef STAGE

    float* x1t = ws + OFF_X1T;
    float* x2t = ws + OFF_X2T;
    float* x3t = ws + OFF_X3T;
#pragma unroll
    for (int mf = 0; mf < 4; mf++) {
        int mloc = mh * 64 + mf * 16 + q * 4;
        int mg = mT * 128 + mloc;
#pragma unroll
        for (int nf = 0; nf < 4; nf++) {
            int n = nT * 128 + nh * 64 + nf * 16 + lidx;
            f32x4 o;
            if (mg < 64) {
#pragma unroll
                for (int r = 0; r < 4; r++)
                    o[r] = ws[OFF_A0 + mg + r] * (acc[mf][nf][r] + b1[mg + r]) + ws[OFF_C0 + mg + r];
                *(f32x4*)(x1t + (b * HWTOT + n) * 64 + mg) = o;
            } else if (mg < 128) {
                int c = mg - 64;
#pragma unroll
                for (int r = 0; r < 4; r++)
                    o[r] = ws[OFF_A0 + c + r] * (acc[mf][nf][r] + b2[c + r]);
                *(f32x4*)(x2t + (b * HWTOT + n) * 64 + c) = o;
            } else {
                int c = mg - 128;
#pragma unroll
                for (int r = 0; r < 4; r++)
                    o[r] = acc[mf][nf][r] + b3[c + r];
                *(f32x4*)(x3t + (b * HWTOT + n) * 512 + c) = o;
            }
        }
    }
}

// Fallback fp32 projection (used only if ws_size is too small for tiles).
__global__ __launch_bounds__(256) void k_proj(
        const float* __restrict__ x,
        const float* __restrict__ w1, const float* __restrict__ b1,
        const float* __restrict__ w2, const float* __restrict__ b2,
        const float* __restrict__ w3, const float* __restrict__ b3,
        float* __restrict__ ws) {
    __shared__ __align__(16) float As[64 * 17];
    __shared__ __align__(16) float Bs[16 * 64];
    int tid = threadIdx.x;
    int n0 = blockIdx.x * 64;
    int mT = blockIdx.y;
    int b = blockIdx.z;
    int mq = tid >> 4, nq = tid & 15;
    float acc[4][4];
#pragma unroll
    for (int i = 0; i < 4; i++)
#pragma unroll
        for (int j = 0; j < 4; j++) acc[i][j] = 0.f;

    for (int k0 = 0; k0 < CIN; k0 += 16) {
#pragma unroll
        for (int i = 0; i < 4; i++) {
            int t = tid + i * 256;
            int k = t & 15, m = t >> 4;
            int mg = mT * 64 + m;
            const float* Wrow;
            if (mg < 64) Wrow = w1 + mg * CIN;
            else if (mg < 128) Wrow = w2 + (mg - 64) * CIN;
            else Wrow = w3 + (mg - 128) * CIN;
            As[m * 17 + k] = Wrow[k0 + k];
        }
#pragma unroll
        for (int i = 0; i < 4; i++) {
            int t = tid + i * 256;
            int n = t & 63, k = t >> 6;
            Bs[k * 64 + n] = x[(b * CIN + k0 + k) * HWTOT + n0 + n];
        }
        __syncthreads();
#pragma unroll
        for (int k = 0; k < 16; k++) {
            float4 bv = *(const float4*)&Bs[k * 64 + nq * 4];
            float av[4];
#pragma unroll
            for (int i = 0; i < 4; i++) av[i] = As[(mq * 4 + i) * 17 + k];
#pragma unroll
            for (int i = 0; i < 4; i++) {
                acc[i][0] += av[i] * bv.x;
                acc[i][1] += av[i] * bv.y;
                acc[i][2] += av[i] * bv.z;
                acc[i][3] += av[i] * bv.w;
            }
        }
        __syncthreads();
    }
    float* x1t = ws + OFF_X1T;
    float* x2t = ws + OFF_X2T;
    float* x3t = ws + OFF_X3T;
#pragma unroll
    for (int i = 0; i < 4; i++) {
        int mg = mT * 64 + mq * 4 + i;
        if (mg < 64) {
            float bias = b1[mg];
            float aa = ws[OFF_A0 + mg], cc = ws[OFF_C0 + mg];
#pragma unroll
            for (int j = 0; j < 4; j++) {
                int n = n0 + nq * 4 + j;
                x1t[(b * HWTOT + n) * 64 + mg] = aa * (acc[i][j] + bias) + cc;
            }
        } else if (mg < 128) {
            int r = mg - 64;
            float bias = b2[r];
            float aa = ws[OFF_A0 + r];
#pragma unroll
            for (int j = 0; j < 4; j++) {
                int n = n0 + nq * 4 + j;
                x2t[(b * HWTOT + n) * 64 + r] = aa * (acc[i][j] + bias);
            }
        } else {
            float bias = b3[mg - 128];
#pragma unroll
            for (int j = 0; j < 4; j++) {
                int n = n0 + nq * 4 + j;
                x3t[(b * HWTOT + n) * 512 + (mg - 128)] = acc[i][j] + bias;
            }
        }
    }
}

// One wave = one pixel. 256 threads = 4 independent waves. One barrier total.
__global__ __launch_bounds__(256, 4) void k_fused(
        const float* __restrict__ ws, float* __restrict__ out) {
    __shared__ __align__(16) char smem[35840];  // 4 waves x (8KB t1/wgt + 768B aux)

    int tid = threadIdx.x;
    int lane = tid & 63;
    int wv = tid >> 6;
    int lidx = lane & 15;
    int q = lane >> 4;

    int p = blockIdx.x * 4 + wv;
    int b = p >> 10;
    int n = p & 1023;
    int y = n >> 5, x0 = n & 31;

    char* t1p = smem + wv * 8960;                       // t1 [64col][64co] bf16 SWZ; later wgt [64g][64k] bf16 SWZ
    float* auxf = (float*)(smem + wv * 8960 + 8192);    // s64[64], s65[64]
    int* nbo = (int*)(smem + wv * 8960 + 8704);         // nbo[64]

    const float* x1t = ws + OFF_X1T;
    const float* x2t = ws + OFF_X2T;
    const float* x3t = ws + OFF_X3T;
    const float* pm  = ws + OFF_PM;
    const unsigned short* w1b = (const unsigned short*)(ws + OFF_W1B);
    const unsigned short* w2f = (const unsigned short*)(ws + OFF_W2F);

    // ---- per-lane neighbor precompute (k = lane, all 64 uniform) ----
    {
        int k = lane;
        int di = k / 7 - 3, dj = k % 7 - 3;
        int nb = refl(y + di) * 32 + refl(x0 + dj);
        nbo[k] = nb;
        float a064 = ws[OFF_A0 + 64], c064 = ws[OFF_C0 + 64];
        float a065 = ws[OFF_A0 + 65], c065 = ws[OFF_C0 + 65];
        auxf[k]      = fmaxf(fmaf(a064, pm[n * 2 + 0] - pm[nb * 2 + 0], c064), 0.f);
        auxf[64 + k] = fmaxf(fmaf(a065, pm[n * 2 + 1] - pm[nb * 2 + 1], c065), 0.f);
    }
    __syncthreads();

    // ---- A-frags (wcw1) + x1 registers ----
    s16x8 af1[4][2];
#pragma unroll
    for (int cot = 0; cot < 4; cot++)
#pragma unroll
        for (int ks = 0; ks < 2; ks++)
            af1[cot][ks] = *(const s16x8*)(w1b + (lidx + 16 * cot) * 64 + ks * 32 + q * 8);

    const float* x1r = x1t + (size_t)(b * HWTOT + n) * 64;
    f32x4 x1v[2][2];
#pragma unroll
    for (int ks = 0; ks < 2; ks++) {
        x1v[ks][0] = *(const f32x4*)(x1r + ks * 32 + q * 8);
        x1v[ks][1] = *(const f32x4*)(x1r + ks * 32 + q * 8 + 4);
    }

    // ---- GEMM1: per col-tile build B in regs, MFMA, epilogue -> t1 LDS ----
#pragma unroll
    for (int ct = 0; ct < 4; ct++) {
        int col = lidx + 16 * ct;
        int nb = nbo[col];
        const float* x2r = x2t + (size_t)(b * HWTOT + nb) * 64;
        f32x4 acc1[4];
#pragma unroll
        for (int cot = 0; cot < 4; cot++) acc1[cot] = (f32x4)0.f;
#pragma unroll
        for (int ks = 0; ks < 2; ks++) {
            f32x4 v0 = *(const f32x4*)(x2r + ks * 32 + q * 8);
            f32x4 v1 = *(const f32x4*)(x2r + ks * 32 + q * 8 + 4);
            union { s16x8 v; unsigned u[4]; } bb;
            bb.u[0] = pk2bf(fmaxf(x1v[ks][0][0] - v0[0], 0.f), fmaxf(x1v[ks][0][1] - v0[1], 0.f));
            bb.u[1] = pk2bf(fmaxf(x1v[ks][0][2] - v0[2], 0.f), fmaxf(x1v[ks][0][3] - v0[3], 0.f));
            bb.u[2] = pk2bf(fmaxf(x1v[ks][1][0] - v1[0], 0.f), fmaxf(x1v[ks][1][1] - v1[1], 0.f));
            bb.u[3] = pk2bf(fmaxf(x1v[ks][1][2] - v1[2], 0.f), fmaxf(x1v[ks][1][3] - v1[3], 0.f));
#pragma unroll
            for (int cot = 0; cot < 4; cot++)
                acc1[cot] = __builtin_amdgcn_mfma_f32_16x16x32_bf16(af1[cot][ks], bb.v, acc1[cot], 0, 0, 0);
        }
        float s64 = auxf[col], s65 = auxf[64 + col];
#pragma unroll
        for (int cot = 0; cot < 4; cot++) {
            f32x4 wa = *(const f32x4*)(ws + OFF_W64 + cot * 16 + q * 4);
            f32x4 wb = *(const f32x4*)(ws + OFF_W65 + cot * 16 + q * 4);
            f32x4 cc = *(const f32x4*)(ws + OFF_C1V + cot * 16 + q * 4);
            float t[4];
#pragma unroll
            for (int r = 0; r < 4; r++)
                t[r] = fmaxf(acc1[cot][r] + wa[r] * s64 + wb[r] * s65 + cc[r], 0.f);
            uint2 pk;
            pk.x = pk2bf(t[0], t[1]);
            pk.y = pk2bf(t[2], t[3]);
            int byte = col * 128 + cot * 32 + q * 8;
            *(uint2*)(t1p + SWZ(byte)) = pk;
        }
    }

    asm volatile("s_waitcnt lgkmcnt(0)" ::: "memory");
    __builtin_amdgcn_sched_barrier(0);

    // ---- GEMM2 (swapped operands: D[k][g]) + softmax over k, per g-tile ----
    s16x8 af2[4][2];
#pragma unroll
    for (int gt = 0; gt < 4; gt++)
#pragma unroll
        for (int ks2 = 0; ks2 < 2; ks2++)
            af2[gt][ks2] = *(const s16x8*)(w2f + ((gt * 2 + ks2) * 64 + lane) * 8);

    unsigned held[4][4][2];
#pragma unroll
    for (int gt = 0; gt < 4; gt++) {
        f32x4 acc2[4];
#pragma unroll
        for (int kt = 0; kt < 4; kt++) acc2[kt] = (f32x4)0.f;
#pragma unroll
        for (int kt = 0; kt < 4; kt++) {
#pragma unroll
            for (int ks2 = 0; ks2 < 2; ks2++) {
                int byte = (lidx + 16 * kt) * 128 + ks2 * 64 + q * 16;
                s16x8 a = *(const s16x8*)(t1p + SWZ(byte));
                acc2[kt] = __builtin_amdgcn_mfma_f32_16x16x32_bf16(a, af2[gt][ks2], acc2[kt], 0, 0, 0);
            }
        }
        // softmax over k = 16*kt + q*4 + r (valid k < 49)
        float mx = -1e30f;
#pragma unroll
        for (int kt = 0; kt < 3; kt++)
#pragma unroll
            for (int r = 0; r < 4; r++) mx = fmaxf(mx, acc2[kt][r]);
        if (q == 0) mx = fmaxf(mx, acc2[3][0]);
        mx = fmaxf(mx, __shfl_xor(mx, 16));
        mx = fmaxf(mx, __shfl_xor(mx, 32));
        float e[4][4];
        float sum = 0.f;
#pragma unroll
        for (int kt = 0; kt < 4; kt++)
#pragma unroll
            for (int r = 0; r < 4; r++) {
                bool valid = (kt < 3) || (q == 0 && r == 0);
                float ev = valid ? exp2f((acc2[kt][r] - mx) * 1.44269504f) : 0.f;
                e[kt][r] = ev;
                sum += ev;
            }
        sum += __shfl_xor(sum, 16);
        sum += __shfl_xor(sum, 32);
        float inv = 1.f / sum;
#pragma unroll
        for (int kt = 0; kt < 4; kt++) {
            held[gt][kt][0] = pk2bf(e[kt][0] * inv, e[kt][1] * inv);
            held[gt][kt][1] = pk2bf(e[kt][2] * inv, e[kt][3] * inv);
        }
    }

    // all t1 reads done -> overwrite buffer with wgt [g][k] bf16
#pragma unroll
    for (int gt = 0; gt < 4; gt++)
#pragma unroll
        for (int kt = 0; kt < 4; kt++) {
            int byte = (lidx + 16 * gt) * 128 + kt * 32 + q * 8;
            uint2 pk;
            pk.x = held[gt][kt][0];
            pk.y = held[gt][kt][1];
            *(uint2*)(t1p + SWZ(byte)) = pk;
        }

    asm volatile("s_waitcnt lgkmcnt(0)" ::: "memory");
    __builtin_amdgcn_sched_barrier(0);

    // ---- aggregation: lane owns 8 channels (g = lane), wgt row pre-read ----
    s16x8 wrow[7];
#pragma unroll
    for (int i = 0; i < 7; i++)
        wrow[i] = *(const s16x8*)(t1p + SWZ(lane * 128 + i * 16));

    f32x4 a30 = (f32x4)0.f, a31 = (f32x4)0.f;
    const float* x3b = x3t + (size_t)b * HWTOT * 512 + lane * 8;
#pragma unroll
    for (int k = 0; k < KKW; k++) {
        int nb = nbo[k];
        float w = bf2f((unsigned short)wrow[k >> 3][k & 7]);
        const float* row = x3b + (size_t)nb * 512;
        f32x4 v0 = *(const f32x4*)(row);
        f32x4 v1 = *(const f32x4*)(row + 4);
#pragma unroll
        for (int r = 0; r < 4; r++) {
            a30[r] = fmaf(w, v0[r], a30[r]);
            a31[r] = fmaf(w, v1[r], a31[r]);
        }
    }
    float* ob = out + ((size_t)b * COUT + lane * 8) * HWTOT + n;
#pragma unroll
    for (int i = 0; i < 4; i++) ob[i * HWTOT] = a30[i];
#pragma unroll
    for (int i = 0; i < 4; i++) ob[(i + 4) * HWTOT] = a31[i];
}

extern "C" void kernel_launch(void* const* d_in, const int* in_sizes, int n_in,
                              void* d_out, int out_size, void* d_ws, size_t ws_size,
                              hipStream_t stream) {
    const float* x = (const float*)d_in[0];
    const float* w1 = (const float*)d_in[1];
    const float* b1 = (const float*)d_in[2];
    const float* w2 = (const float*)d_in[3];
    const float* b2 = (const float*)d_in[4];
    const float* w3 = (const float*)d_in[5];
    const float* b3 = (const float*)d_in[6];
    const float* wp = (const float*)d_in[7];
    const float* bp = (const float*)d_in[8];
    const float* g0 = (const float*)d_in[9];
    const float* be0 = (const float*)d_in[10];
    const float* m0 = (const float*)d_in[11];
    const float* v0 = (const float*)d_in[12];
    const float* wcw1 = (const float*)d_in[13];
    const float* g1 = (const float*)d_in[14];
    const float* be1 = (const float*)d_in[15];
    const float* m1 = (const float*)d_in[16];
    const float* v1 = (const float*)d_in[17];
    const float* wcw2 = (const float*)d_in[18];
    float* ws = (float*)d_ws;
    float* out = (float*)d_out;

    k_setup<<<1, 256, 0, stream>>>(wp, bp, g0, be0, m0, v0, wcw1, g1, be1, m1, v1, wcw2, ws);
    if (ws_size >= WS_NEED_FLOATS * 4ull) {
        k_prep<<<296, 256, 0, stream>>>(x, w1, w2, w3, ws);
        k_projm<<<dim3(5, 8, 4), 256, 0, stream>>>(b1, b2, b3, ws);
    } else {
        k_proj<<<dim3(16, 10, 4), 256, 0, stream>>>(x, w1, b1, w2, b2, w3, b3, ws);
    }
    k_fused<<<1024, 256, 0, stream>>>(ws, out);
}

// Round 6
// 65.408 us; speedup vs baseline: 5.0926x; 1.1295x over previous
//
#include <hip/hip_runtime.h>
#include <hip/hip_bf16.h>
#include <math.h>

typedef float f32x4 __attribute__((ext_vector_type(4)));
typedef short s16x8 __attribute__((ext_vector_type(8)));

#define KKW 49
#define HWTOT 1024
#define CIN 512
#define COUT 512

// ws float offsets (x1t/x2t/x3t regions now hold bf16, same offsets)
#define OFF_X1T 0
#define OFF_X2T 262144
#define OFF_X3T 524288
#define OFF_PM  2621440
#define OFF_A0  2623488
#define OFF_C0  2623554
#define OFF_W64 2623620
#define OFF_W65 2623684
#define OFF_C1V 2623748
#define OFF_W1B 2623812   /* 4096 bf16 (a1-folded wcw1[:, :64]) */
#define OFF_W2B 2625860   /* reserved */
#define OFF_W2F 2627908   /* 4096 bf16 (wcw2^T pre-fragmented for GEMM2 B) */
#define OFF_WT  2629956   /* 640x512 bf16, 5x8 tiles of [128m][64k] swizzled */
#define OFF_XT  2793796   /* 4x1024x512 bf16, 4x8x8 tiles of [128n][64k] swizzled */
#define WS_NEED_FLOATS 3842372ull

#define SWZ(bb)  ((bb) ^ ((((bb) >> 7) & 7) << 4))

#define GLD16(g, l) __builtin_amdgcn_global_load_lds( \
    (const __attribute__((address_space(1))) void*)(g), \
    (__attribute__((address_space(3))) void*)(l), 16, 0, 0)

__device__ __forceinline__ int refl(int m) {
    if (m < 0) m = -m;
    if (m > 31) m = 62 - m;
    return m;
}

__device__ __forceinline__ unsigned short fbf(float f) {
    unsigned u = __builtin_bit_cast(unsigned, f);
    unsigned r = u + 0x7fffu + ((u >> 16) & 1u);
    return (unsigned short)(r >> 16);
}

__device__ __forceinline__ unsigned pk2bf(float a, float b) {
    float2 f2; f2.x = a; f2.y = b;
    __hip_bfloat162 h = __float22bfloat162_rn(f2);
    union { __hip_bfloat162 h2; unsigned u; } cv;
    cv.h2 = h;
    return cv.u;
}

__device__ __forceinline__ float bf2f(unsigned short u) {
    unsigned v = (unsigned)u << 16;
    return __builtin_bit_cast(float, v);
}

__global__ void k_setup(const float* __restrict__ wp, const float* __restrict__ bp,
                        const float* __restrict__ g0, const float* __restrict__ be0,
                        const float* __restrict__ m0, const float* __restrict__ v0,
                        const float* __restrict__ wcw1,
                        const float* __restrict__ g1, const float* __restrict__ be1,
                        const float* __restrict__ m1, const float* __restrict__ v1,
                        const float* __restrict__ wcw2,
                        float* __restrict__ ws) {
    int tid = threadIdx.x;
    float* pm = ws + OFF_PM;
    for (int n = tid; n < HWTOT; n += 256) {
        int xx = n & 31, yy = n >> 5;
        float lw = -1.f + (2.f / 31.f) * xx;
        float lh = -1.f + (2.f / 31.f) * yy;
        pm[n * 2 + 0] = wp[0] * lw + wp[1] * lh + bp[0];
        pm[n * 2 + 1] = wp[2] * lw + wp[3] * lh + bp[1];
    }
    if (tid < 66) {
        float a = g0[tid] * rsqrtf(v0[tid] + 1e-5f);
        ws[OFF_A0 + tid] = a;
        ws[OFF_C0 + tid] = be0[tid] - m0[tid] * a;
    }
    if (tid < 64) {
        float a1c = g1[tid] * rsqrtf(v1[tid] + 1e-5f);
        ws[OFF_W64 + tid] = a1c * wcw1[tid * 66 + 64];
        ws[OFF_W65 + tid] = a1c * wcw1[tid * 66 + 65];
        ws[OFF_C1V + tid] = be1[tid] - m1[tid] * a1c;
    }
    unsigned short* w1b = (unsigned short*)(ws + OFF_W1B);
    unsigned short* w2f = (unsigned short*)(ws + OFF_W2F);
    for (int t = tid; t < 4096; t += 256) {
        int co = t >> 6, r = t & 63;
        float a1c = g1[co] * rsqrtf(v1[co] + 1e-5f);
        w1b[t] = fbf(a1c * wcw1[co * 66 + r]);
        // pre-fragmented wcw2^T for GEMM2 B-operand: frag ft=(gt*2+ks2), lane l, elem j
        int j = t & 7, idx = t >> 3;
        int ft = idx >> 6, l = idx & 63;
        int gt = ft >> 1, ks2 = ft & 1;
        int g = (l & 15) + gt * 16;
        int c2 = ks2 * 32 + (l >> 4) * 8 + j;
        w2f[t] = fbf(wcw2[g * 64 + c2]);
    }
}

// Pack weights (blocks 0..39) and x-transpose (blocks 40..295) into swizzled bf16 tiles.
__global__ __launch_bounds__(256) void k_prep(
        const float* __restrict__ x,
        const float* __restrict__ w1, const float* __restrict__ w2,
        const float* __restrict__ w3, float* __restrict__ ws) {
    int bid = blockIdx.x;
    int tid = threadIdx.x;
    if (bid < 40) {
        int mT = bid / 8, kT = bid % 8;
        char* dst = (char*)(ws + OFF_WT) + (mT * 8 + kT) * 16384;
#pragma unroll
        for (int it = 0; it < 4; ++it) {
            int item = it * 256 + tid;
            int m = item >> 3, k8 = item & 7;
            int mg = mT * 128 + m;
            const float* src;
            if (mg < 64) src = w1 + mg * CIN;
            else if (mg < 128) src = w2 + (mg - 64) * CIN;
            else src = w3 + (mg - 128) * CIN;
            int k0 = kT * 64 + k8 * 8;
            s16x8 h;
#pragma unroll
            for (int i = 0; i < 8; i++) h[i] = (short)fbf(src[k0 + i]);
            *(s16x8*)(dst + SWZ(m * 128 + k8 * 16)) = h;
        }
    } else {
        __shared__ float lds[64 * 129];
        int t = bid - 40;  // b(4) nT(8) kT(8)
        int b = t >> 6, nT = (t >> 3) & 7, kT = t & 7;
        const float* src = x + (b * CIN + kT * 64) * HWTOT + nT * 128;
#pragma unroll
        for (int it = 0; it < 8; ++it) {
            int item = it * 256 + tid;
            int kk = item >> 5, n4 = item & 31;
            float4 v = *(const float4*)(src + kk * HWTOT + n4 * 4);
            float* d = &lds[kk * 129 + n4 * 4];
            d[0] = v.x; d[1] = v.y; d[2] = v.z; d[3] = v.w;
        }
        __syncthreads();
        char* dst = (char*)(ws + OFF_XT) + ((b * 8 + nT) * 8 + kT) * 16384;
#pragma unroll
        for (int it = 0; it < 4; ++it) {
            int item = it * 256 + tid;
            int n = item >> 3, k8 = item & 7;
            s16x8 h;
#pragma unroll
            for (int i = 0; i < 8; i++) h[i] = (short)fbf(lds[(k8 * 8 + i) * 129 + n]);
            *(s16x8*)(dst + SWZ(n * 128 + k8 * 16)) = h;
        }
    }
}

// MFMA projection GEMM: C[640 x 1024] = W x X per batch. 128x128 tile, BK=64, dbuf LDS.
// Epilogue writes bf16 x1t/x2t/x3t.
__global__ __launch_bounds__(256) void k_projm(
        const float* __restrict__ b1, const float* __restrict__ b2,
        const float* __restrict__ b3, float* __restrict__ ws) {
    __shared__ __align__(16) char smem[65536];
    int tid = threadIdx.x, lane = tid & 63, wv = tid >> 6;
    int lidx = lane & 15, q = lane >> 4;
    int mT = blockIdx.x, nT = blockIdx.y, b = blockIdx.z;
    int mh = wv >> 1, nh = wv & 1;
    const char* wtg = (const char*)(ws + OFF_WT) + mT * 8 * 16384;
    const char* xtg = (const char*)(ws + OFF_XT) + (b * 8 + nT) * 8 * 16384;

    f32x4 acc[4][4];
#pragma unroll
    for (int i = 0; i < 4; i++)
#pragma unroll
        for (int j = 0; j < 4; j++) acc[i][j] = (f32x4)0.f;

#define STAGE(kt, buf) do { \
        const char* ga_ = wtg + (kt) * 16384; \
        const char* gb_ = xtg + (kt) * 16384; \
        char* la_ = smem + (buf) * 32768; \
        char* lb_ = la_ + 16384; \
        _Pragma("unroll") \
        for (int c_ = 0; c_ < 4; c_++) { \
            GLD16(ga_ + c_ * 4096 + wv * 1024 + lane * 16, la_ + c_ * 4096 + wv * 1024); \
            GLD16(gb_ + c_ * 4096 + wv * 1024 + lane * 16, lb_ + c_ * 4096 + wv * 1024); \
        } \
    } while (0)

    STAGE(0, 0);
    __syncthreads();
    for (int kt = 0; kt < 8; kt++) {
        if (kt < 7) STAGE(kt + 1, (kt + 1) & 1);
        const char* la = smem + (kt & 1) * 32768;
        const char* lb = la + 16384;
#pragma unroll
        for (int ks = 0; ks < 2; ks++) {
            s16x8 af[4], bf[4];
            int kb = ks * 64 + q * 16;
#pragma unroll
            for (int f = 0; f < 4; f++) {
                int arow = mh * 64 + f * 16 + lidx;
                int brow = nh * 64 + f * 16 + lidx;
                af[f] = *(const s16x8*)(la + SWZ(arow * 128 + kb));
                bf[f] = *(const s16x8*)(lb + SWZ(brow * 128 + kb));
            }
#pragma unroll
            for (int mf = 0; mf < 4; mf++)
#pragma unroll
                for (int nf = 0; nf < 4; nf++)
                    acc[mf][nf] = __builtin_amdgcn_mfma_f32_16x16x32_bf16(
                        af[mf], bf[nf], acc[mf][nf], 0, 0, 0);
        }
        __syncthreads();
    }
#undef STAGE

    unsigned short* x1t = (unsigned short*)(ws + OFF_X1T);
    unsigned short* x2t = (unsigned short*)(ws + OFF_X2T);
    unsigned short* x3t = (unsigned short*)(ws + OFF_X3T);
#pragma unroll
    for (int mf = 0; mf < 4; mf++) {
        int mloc = mh * 64 + mf * 16 + q * 4;
        int mg = mT * 128 + mloc;
#pragma unroll
        for (int nf = 0; nf < 4; nf++) {
            int n = nT * 128 + nh * 64 + nf * 16 + lidx;
            float o[4];
            uint2 pk;
            if (mg < 64) {
#pragma unroll
                for (int r = 0; r < 4; r++)
                    o[r] = ws[OFF_A0 + mg + r] * (acc[mf][nf][r] + b1[mg + r]) + ws[OFF_C0 + mg + r];
                pk.x = pk2bf(o[0], o[1]); pk.y = pk2bf(o[2], o[3]);
                *(uint2*)(x1t + (size_t)(b * HWTOT + n) * 64 + mg) = pk;
            } else if (mg < 128) {
                int c = mg - 64;
#pragma unroll
                for (int r = 0; r < 4; r++)
                    o[r] = ws[OFF_A0 + c + r] * (acc[mf][nf][r] + b2[c + r]);
                pk.x = pk2bf(o[0], o[1]); pk.y = pk2bf(o[2], o[3]);
                *(uint2*)(x2t + (size_t)(b * HWTOT + n) * 64 + c) = pk;
            } else {
                int c = mg - 128;
#pragma unroll
                for (int r = 0; r < 4; r++)
                    o[r] = acc[mf][nf][r] + b3[c + r];
                pk.x = pk2bf(o[0], o[1]); pk.y = pk2bf(o[2], o[3]);
                *(uint2*)(x3t + (size_t)(b * HWTOT + n) * 512 + c) = pk;
            }
        }
    }
}

// Fallback fp32 projection (used only if ws_size is too small for tiles); bf16 outputs.
__global__ __launch_bounds__(256) void k_proj(
        const float* __restrict__ x,
        const float* __restrict__ w1, const float* __restrict__ b1,
        const float* __restrict__ w2, const float* __restrict__ b2,
        const float* __restrict__ w3, const float* __restrict__ b3,
        float* __restrict__ ws) {
    __shared__ __align__(16) float As[64 * 17];
    __shared__ __align__(16) float Bs[16 * 64];
    int tid = threadIdx.x;
    int n0 = blockIdx.x * 64;
    int mT = blockIdx.y;
    int b = blockIdx.z;
    int mq = tid >> 4, nq = tid & 15;
    float acc[4][4];
#pragma unroll
    for (int i = 0; i < 4; i++)
#pragma unroll
        for (int j = 0; j < 4; j++) acc[i][j] = 0.f;

    for (int k0 = 0; k0 < CIN; k0 += 16) {
#pragma unroll
        for (int i = 0; i < 4; i++) {
            int t = tid + i * 256;
            int k = t & 15, m = t >> 4;
            int mg = mT * 64 + m;
            const float* Wrow;
            if (mg < 64) Wrow = w1 + mg * CIN;
            else if (mg < 128) Wrow = w2 + (mg - 64) * CIN;
            else Wrow = w3 + (mg - 128) * CIN;
            As[m * 17 + k] = Wrow[k0 + k];
        }
#pragma unroll
        for (int i = 0; i < 4; i++) {
            int t = tid + i * 256;
            int n = t & 63, k = t >> 6;
            Bs[k * 64 + n] = x[(b * CIN + k0 + k) * HWTOT + n0 + n];
        }
        __syncthreads();
#pragma unroll
        for (int k = 0; k < 16; k++) {
            float4 bv = *(const float4*)&Bs[k * 64 + nq * 4];
            float av[4];
#pragma unroll
            for (int i = 0; i < 4; i++) av[i] = As[(mq * 4 + i) * 17 + k];
#pragma unroll
            for (int i = 0; i < 4; i++) {
                acc[i][0] += av[i] * bv.x;
                acc[i][1] += av[i] * bv.y;
                acc[i][2] += av[i] * bv.z;
                acc[i][3] += av[i] * bv.w;
            }
        }
        __syncthreads();
    }
    unsigned short* x1t = (unsigned short*)(ws + OFF_X1T);
    unsigned short* x2t = (unsigned short*)(ws + OFF_X2T);
    unsigned short* x3t = (unsigned short*)(ws + OFF_X3T);
#pragma unroll
    for (int i = 0; i < 4; i++) {
        int mg = mT * 64 + mq * 4 + i;
        if (mg < 64) {
            float bias = b1[mg];
            float aa = ws[OFF_A0 + mg], cc = ws[OFF_C0 + mg];
#pragma unroll
            for (int j = 0; j < 4; j++) {
                int n = n0 + nq * 4 + j;
                x1t[(size_t)(b * HWTOT + n) * 64 + mg] = fbf(aa * (acc[i][j] + bias) + cc);
            }
        } else if (mg < 128) {
            int r = mg - 64;
            float bias = b2[r];
            float aa = ws[OFF_A0 + r];
#pragma unroll
            for (int j = 0; j < 4; j++) {
                int n = n0 + nq * 4 + j;
                x2t[(size_t)(b * HWTOT + n) * 64 + r] = fbf(aa * (acc[i][j] + bias));
            }
        } else {
            float bias = b3[mg - 128];
#pragma unroll
            for (int j = 0; j < 4; j++) {
                int n = n0 + nq * 4 + j;
                x3t[(size_t)(b * HWTOT + n) * 512 + (mg - 128)] = fbf(acc[i][j] + bias);
            }
        }
    }
}

// One wave = one pixel. 256 threads = 4 independent waves. XCD-chunked block swizzle.
__global__ __launch_bounds__(256, 4) void k_fused(
        const float* __restrict__ ws, float* __restrict__ out) {
    __shared__ __align__(16) char smem[35840];  // 4 waves x (8KB t1/wgt + 768B aux)

    int tid = threadIdx.x;
    int lane = tid & 63;
    int wv = tid >> 6;
    int lidx = lane & 15;
    int q = lane >> 4;

    int bid = blockIdx.x;
    int gsw = (bid & 7) * 128 + (bid >> 3);   // XCD k -> contiguous pixel chunk
    int p = gsw * 4 + wv;
    int b = p >> 10;
    int n = p & 1023;
    int y = n >> 5, x0 = n & 31;

    char* t1p = smem + wv * 8960;                       // t1 [64col][64co] bf16 SWZ; later wgt [64g][64k] bf16 SWZ
    float* auxf = (float*)(smem + wv * 8960 + 8192);    // s64[64], s65[64]
    int* nbo = (int*)(smem + wv * 8960 + 8704);         // nbo[64]

    const unsigned short* x1t = (const unsigned short*)(ws + OFF_X1T);
    const unsigned short* x2t = (const unsigned short*)(ws + OFF_X2T);
    const unsigned short* x3t = (const unsigned short*)(ws + OFF_X3T);
    const float* pm  = ws + OFF_PM;
    const unsigned short* w1b = (const unsigned short*)(ws + OFF_W1B);
    const unsigned short* w2f = (const unsigned short*)(ws + OFF_W2F);

    // ---- per-lane neighbor precompute (k = lane, all 64 uniform) ----
    {
        int k = lane;
        int di = k / 7 - 3, dj = k % 7 - 3;
        int nb = refl(y + di) * 32 + refl(x0 + dj);
        nbo[k] = nb;
        float a064 = ws[OFF_A0 + 64], c064 = ws[OFF_C0 + 64];
        float a065 = ws[OFF_A0 + 65], c065 = ws[OFF_C0 + 65];
        auxf[k]      = fmaxf(fmaf(a064, pm[n * 2 + 0] - pm[nb * 2 + 0], c064), 0.f);
        auxf[64 + k] = fmaxf(fmaf(a065, pm[n * 2 + 1] - pm[nb * 2 + 1], c065), 0.f);
    }
    __syncthreads();

    // ---- A-frags (wcw1) + x1 registers ----
    s16x8 af1[4][2];
#pragma unroll
    for (int cot = 0; cot < 4; cot++)
#pragma unroll
        for (int ks = 0; ks < 2; ks++)
            af1[cot][ks] = *(const s16x8*)(w1b + (lidx + 16 * cot) * 64 + ks * 32 + q * 8);

    const unsigned short* x1r = x1t + (size_t)(b * HWTOT + n) * 64 + q * 8;
    float x1f[2][8];
    {
        s16x8 h0 = *(const s16x8*)(x1r);
        s16x8 h1 = *(const s16x8*)(x1r + 32);
#pragma unroll
        for (int i = 0; i < 8; i++) {
            x1f[0][i] = bf2f((unsigned short)h0[i]);
            x1f[1][i] = bf2f((unsigned short)h1[i]);
        }
    }

    // ---- GEMM1: per col-tile build B in regs, MFMA, epilogue -> t1 LDS ----
#pragma unroll
    for (int ct = 0; ct < 4; ct++) {
        int col = lidx + 16 * ct;
        int nb = nbo[col];
        const unsigned short* x2r = x2t + (size_t)(b * HWTOT + nb) * 64 + q * 8;
        f32x4 acc1[4];
#pragma unroll
        for (int cot = 0; cot < 4; cot++) acc1[cot] = (f32x4)0.f;
#pragma unroll
        for (int ks = 0; ks < 2; ks++) {
            s16x8 v = *(const s16x8*)(x2r + ks * 32);
            union { s16x8 v; unsigned u[4]; } bb;
#pragma unroll
            for (int w = 0; w < 4; w++)
                bb.u[w] = pk2bf(
                    fmaxf(x1f[ks][2 * w]     - bf2f((unsigned short)v[2 * w]),     0.f),
                    fmaxf(x1f[ks][2 * w + 1] - bf2f((unsigned short)v[2 * w + 1]), 0.f));
#pragma unroll
            for (int cot = 0; cot < 4; cot++)
                acc1[cot] = __builtin_amdgcn_mfma_f32_16x16x32_bf16(af1[cot][ks], bb.v, acc1[cot], 0, 0, 0);
        }
        float s64 = auxf[col], s65 = auxf[64 + col];
#pragma unroll
        for (int cot = 0; cot < 4; cot++) {
            f32x4 wa = *(const f32x4*)(ws + OFF_W64 + cot * 16 + q * 4);
            f32x4 wb = *(const f32x4*)(ws + OFF_W65 + cot * 16 + q * 4);
            f32x4 cc = *(const f32x4*)(ws + OFF_C1V + cot * 16 + q * 4);
            float t[4];
#pragma unroll
            for (int r = 0; r < 4; r++)
                t[r] = fmaxf(acc1[cot][r] + wa[r] * s64 + wb[r] * s65 + cc[r], 0.f);
            uint2 pk;
            pk.x = pk2bf(t[0], t[1]);
            pk.y = pk2bf(t[2], t[3]);
            int byte = col * 128 + cot * 32 + q * 8;
            *(uint2*)(t1p + SWZ(byte)) = pk;
        }
    }

    asm volatile("s_waitcnt lgkmcnt(0)" ::: "memory");
    __builtin_amdgcn_sched_barrier(0);

    // ---- GEMM2 (swapped operands: D[k][g]) + softmax over k, per g-tile ----
    s16x8 af2[4][2];
#pragma unroll
    for (int gt = 0; gt < 4; gt++)
#pragma unroll
        for (int ks2 = 0; ks2 < 2; ks2++)
            af2[gt][ks2] = *(const s16x8*)(w2f + ((gt * 2 + ks2) * 64 + lane) * 8);

    unsigned held[4][4][2];
#pragma unroll
    for (int gt = 0; gt < 4; gt++) {
        f32x4 acc2[4];
#pragma unroll
        for (int kt = 0; kt < 4; kt++) acc2[kt] = (f32x4)0.f;
#pragma unroll
        for (int kt = 0; kt < 4; kt++) {
#pragma unroll
            for (int ks2 = 0; ks2 < 2; ks2++) {
                int byte = (lidx + 16 * kt) * 128 + ks2 * 64 + q * 16;
                s16x8 a = *(const s16x8*)(t1p + SWZ(byte));
                acc2[kt] = __builtin_amdgcn_mfma_f32_16x16x32_bf16(a, af2[gt][ks2], acc2[kt], 0, 0, 0);
            }
        }
        // softmax over k = 16*kt + q*4 + r (valid k < 49)
        float mx = -1e30f;
#pragma unroll
        for (int kt = 0; kt < 3; kt++)
#pragma unroll
            for (int r = 0; r < 4; r++) mx = fmaxf(mx, acc2[kt][r]);
        if (q == 0) mx = fmaxf(mx, acc2[3][0]);
        mx = fmaxf(mx, __shfl_xor(mx, 16));
        mx = fmaxf(mx, __shfl_xor(mx, 32));
        float e[4][4];
        float sum = 0.f;
#pragma unroll
        for (int kt = 0; kt < 4; kt++)
#pragma unroll
            for (int r = 0; r < 4; r++) {
                bool valid = (kt < 3) || (q == 0 && r == 0);
                float ev = valid ? exp2f((acc2[kt][r] - mx) * 1.44269504f) : 0.f;
                e[kt][r] = ev;
                sum += ev;
            }
        sum += __shfl_xor(sum, 16);
        sum += __shfl_xor(sum, 32);
        float inv = 1.f / sum;
#pragma unroll
        for (int kt = 0; kt < 4; kt++) {
            held[gt][kt][0] = pk2bf(e[kt][0] * inv, e[kt][1] * inv);
            held[gt][kt][1] = pk2bf(e[kt][2] * inv, e[kt][3] * inv);
        }
    }

    // all t1 reads done -> overwrite buffer with wgt [g][k] bf16
#pragma unroll
    for (int gt = 0; gt < 4; gt++)
#pragma unroll
        for (int kt = 0; kt < 4; kt++) {
            int byte = (lidx + 16 * gt) * 128 + kt * 32 + q * 8;
            uint2 pk;
            pk.x = held[gt][kt][0];
            pk.y = held[gt][kt][1];
            *(uint2*)(t1p + SWZ(byte)) = pk;
        }

    asm volatile("s_waitcnt lgkmcnt(0)" ::: "memory");
    __builtin_amdgcn_sched_barrier(0);

    // ---- aggregation: lane owns 8 channels (g = lane), wgt row pre-read ----
    s16x8 wrow[7];
#pragma unroll
    for (int i = 0; i < 7; i++)
        wrow[i] = *(const s16x8*)(t1p + SWZ(lane * 128 + i * 16));

    f32x4 a30 = (f32x4)0.f, a31 = (f32x4)0.f;
    const unsigned short* x3b = x3t + (size_t)b * HWTOT * 512 + lane * 8;
#pragma unroll
    for (int k = 0; k < KKW; k++) {
        int nb = nbo[k];
        float w = bf2f((unsigned short)wrow[k >> 3][k & 7]);
        s16x8 v = *(const s16x8*)(x3b + (size_t)nb * 512);
#pragma unroll
        for (int r = 0; r < 4; r++) {
            a30[r] = fmaf(w, bf2f((unsigned short)v[r]), a30[r]);
            a31[r] = fmaf(w, bf2f((unsigned short)v[4 + r]), a31[r]);
        }
    }
    float* ob = out + ((size_t)b * COUT + lane * 8) * HWTOT + n;
#pragma unroll
    for (int i = 0; i < 4; i++) ob[i * HWTOT] = a30[i];
#pragma unroll
    for (int i = 0; i < 4; i++) ob[(i + 4) * HWTOT] = a31[i];
}

extern "C" void kernel_launch(void* const* d_in, const int* in_sizes, int n_in,
                              void* d_out, int out_size, void* d_ws, size_t ws_size,
                              hipStream_t stream) {
    const float* x = (const float*)d_in[0];
    const float* w1 = (const float*)d_in[1];
    const float* b1 = (const float*)d_in[2];
    const float* w2 = (const float*)d_in[3];
    const float* b2 = (const float*)d_in[4];
    const float* w3 = (const float*)d_in[5];
    const float* b3 = (const float*)d_in[6];
    const float* wp = (const float*)d_in[7];
    const float* bp = (const float*)d_in[8];
    const float* g0 = (const float*)d_in[9];
    const float* be0 = (const float*)d_in[10];
    const float* m0 = (const float*)d_in[11];
    const float* v0 = (const float*)d_in[12];
    const float* wcw1 = (const float*)d_in[13];
    const float* g1 = (const float*)d_in[14];
    const float* be1 = (const float*)d_in[15];
    const float* m1 = (const float*)d_in[16];
    const float* v1 = (const float*)d_in[17];
    const float* wcw2 = (const float*)d_in[18];
    float* ws = (float*)d_ws;
    float* out = (float*)d_out;

    k_setup<<<1, 256, 0, stream>>>(wp, bp, g0, be0, m0, v0, wcw1, g1, be1, m1, v1, wcw2, ws);
    if (ws_size >= WS_NEED_FLOATS * 4ull) {
        k_prep<<<296, 256, 0, stream>>>(x, w1, w2, w3, ws);
        k_projm<<<dim3(5, 8, 4), 256, 0, stream>>>(b1, b2, b3, ws);
    } else {
        k_proj<<<dim3(16, 10, 4), 256, 0, stream>>>(x, w1, b1, w2, b2, w3, b3, ws);
    }
    k_fused<<<1024, 256, 0, stream>>>(ws, out);
}

// Round 7
// 62.328 us; speedup vs baseline: 5.3443x; 1.0494x over previous
//
#include <hip/hip_runtime.h>
#include <hip/hip_bf16.h>
#include <math.h>

typedef float f32x4 __attribute__((ext_vector_type(4)));
typedef short s16x8 __attribute__((ext_vector_type(8)));

#define KKW 49
#define HWTOT 1024
#define CIN 512
#define COUT 512

// ws float offsets (x1t/x2t/x3t regions hold bf16)
#define OFF_X1T 0
#define OFF_X2T 262144
#define OFF_X3T 524288
#define OFF_PM  2621440
#define OFF_A0  2623488
#define OFF_C0  2623554
#define OFF_W64 2623620
#define OFF_W65 2623684
#define OFF_C1V 2623748
#define OFF_W1B 2623812   /* 4096 bf16 (a1-folded wcw1[:, :64]) */
#define OFF_W2B 2625860   /* reserved */
#define OFF_W2F 2627908   /* 4096 bf16 (wcw2^T pre-fragmented for GEMM2 B) */
#define OFF_WT  2629956   /* 640x512 bf16, 5x8 tiles of [128m][64k] swizzled */
#define OFF_XT  2793796   /* 4x1024x512 bf16, 4x8x8 tiles of [128n][64k] swizzled */
#define WS_NEED_FLOATS 3842372ull

#define SWZ(bb)  ((bb) ^ ((((bb) >> 7) & 7) << 4))

#define GLD16(g, l) __builtin_amdgcn_global_load_lds( \
    (const __attribute__((address_space(1))) void*)(g), \
    (__attribute__((address_space(3))) void*)(l), 16, 0, 0)

__device__ __forceinline__ int refl(int m) {
    if (m < 0) m = -m;
    if (m > 31) m = 62 - m;
    return m;
}

__device__ __forceinline__ unsigned short fbf(float f) {
    unsigned u = __builtin_bit_cast(unsigned, f);
    unsigned r = u + 0x7fffu + ((u >> 16) & 1u);
    return (unsigned short)(r >> 16);
}

__device__ __forceinline__ unsigned pk2bf(float a, float b) {
    float2 f2; f2.x = a; f2.y = b;
    __hip_bfloat162 h = __float22bfloat162_rn(f2);
    union { __hip_bfloat162 h2; unsigned u; } cv;
    cv.h2 = h;
    return cv.u;
}

__device__ __forceinline__ float bf2f(unsigned short u) {
    unsigned v = (unsigned)u << 16;
    return __builtin_bit_cast(float, v);
}

__device__ __forceinline__ void setup_body(
        int tid,
        const float* __restrict__ wp, const float* __restrict__ bp,
        const float* __restrict__ g0, const float* __restrict__ be0,
        const float* __restrict__ m0, const float* __restrict__ v0,
        const float* __restrict__ wcw1,
        const float* __restrict__ g1, const float* __restrict__ be1,
        const float* __restrict__ m1, const float* __restrict__ v1,
        const float* __restrict__ wcw2,
        float* __restrict__ ws) {
    float* pm = ws + OFF_PM;
    for (int n = tid; n < HWTOT; n += 256) {
        int xx = n & 31, yy = n >> 5;
        float lw = -1.f + (2.f / 31.f) * xx;
        float lh = -1.f + (2.f / 31.f) * yy;
        pm[n * 2 + 0] = wp[0] * lw + wp[1] * lh + bp[0];
        pm[n * 2 + 1] = wp[2] * lw + wp[3] * lh + bp[1];
    }
    if (tid < 66) {
        float a = g0[tid] * rsqrtf(v0[tid] + 1e-5f);
        ws[OFF_A0 + tid] = a;
        ws[OFF_C0 + tid] = be0[tid] - m0[tid] * a;
    }
    if (tid < 64) {
        float a1c = g1[tid] * rsqrtf(v1[tid] + 1e-5f);
        ws[OFF_W64 + tid] = a1c * wcw1[tid * 66 + 64];
        ws[OFF_W65 + tid] = a1c * wcw1[tid * 66 + 65];
        ws[OFF_C1V + tid] = be1[tid] - m1[tid] * a1c;
    }
    unsigned short* w1b = (unsigned short*)(ws + OFF_W1B);
    unsigned short* w2f = (unsigned short*)(ws + OFF_W2F);
    for (int t = tid; t < 4096; t += 256) {
        int co = t >> 6, r = t & 63;
        float a1c = g1[co] * rsqrtf(v1[co] + 1e-5f);
        w1b[t] = fbf(a1c * wcw1[co * 66 + r]);
        int j = t & 7, idx = t >> 3;
        int ft = idx >> 6, l = idx & 63;
        int gt = ft >> 1, ks2 = ft & 1;
        int g = (l & 15) + gt * 16;
        int c2 = ks2 * 32 + (l >> 4) * 8 + j;
        w2f[t] = fbf(wcw2[g * 64 + c2]);
    }
}

__global__ void k_setup(const float* __restrict__ wp, const float* __restrict__ bp,
                        const float* __restrict__ g0, const float* __restrict__ be0,
                        const float* __restrict__ m0, const float* __restrict__ v0,
                        const float* __restrict__ wcw1,
                        const float* __restrict__ g1, const float* __restrict__ be1,
                        const float* __restrict__ m1, const float* __restrict__ v1,
                        const float* __restrict__ wcw2,
                        float* __restrict__ ws) {
    setup_body(threadIdx.x, wp, bp, g0, be0, m0, v0, wcw1, g1, be1, m1, v1, wcw2, ws);
}

// Pack weights (blocks 0..39), x-transpose (blocks 40..295), setup (block 296).
__global__ __launch_bounds__(256) void k_prep(
        const float* __restrict__ x,
        const float* __restrict__ w1, const float* __restrict__ w2,
        const float* __restrict__ w3,
        const float* __restrict__ wp, const float* __restrict__ bp,
        const float* __restrict__ g0, const float* __restrict__ be0,
        const float* __restrict__ m0, const float* __restrict__ v0,
        const float* __restrict__ wcw1,
        const float* __restrict__ g1, const float* __restrict__ be1,
        const float* __restrict__ m1, const float* __restrict__ v1,
        const float* __restrict__ wcw2,
        float* __restrict__ ws) {
    int bid = blockIdx.x;
    int tid = threadIdx.x;
    if (bid == 296) {
        setup_body(tid, wp, bp, g0, be0, m0, v0, wcw1, g1, be1, m1, v1, wcw2, ws);
    } else if (bid < 40) {
        int mT = bid / 8, kT = bid % 8;
        char* dst = (char*)(ws + OFF_WT) + (mT * 8 + kT) * 16384;
#pragma unroll
        for (int it = 0; it < 4; ++it) {
            int item = it * 256 + tid;
            int m = item >> 3, k8 = item & 7;
            int mg = mT * 128 + m;
            const float* src;
            if (mg < 64) src = w1 + mg * CIN;
            else if (mg < 128) src = w2 + (mg - 64) * CIN;
            else src = w3 + (mg - 128) * CIN;
            int k0 = kT * 64 + k8 * 8;
            s16x8 h;
#pragma unroll
            for (int i = 0; i < 8; i++) h[i] = (short)fbf(src[k0 + i]);
            *(s16x8*)(dst + SWZ(m * 128 + k8 * 16)) = h;
        }
    } else {
        __shared__ float lds[64 * 129];
        int t = bid - 40;  // b(4) nT(8) kT(8)
        int b = t >> 6, nT = (t >> 3) & 7, kT = t & 7;
        const float* src = x + (b * CIN + kT * 64) * HWTOT + nT * 128;
#pragma unroll
        for (int it = 0; it < 8; ++it) {
            int item = it * 256 + tid;
            int kk = item >> 5, n4 = item & 31;
            float4 v = *(const float4*)(src + kk * HWTOT + n4 * 4);
            float* d = &lds[kk * 129 + n4 * 4];
            d[0] = v.x; d[1] = v.y; d[2] = v.z; d[3] = v.w;
        }
        __syncthreads();
        char* dst = (char*)(ws + OFF_XT) + ((b * 8 + nT) * 8 + kT) * 16384;
#pragma unroll
        for (int it = 0; it < 4; ++it) {
            int item = it * 256 + tid;
            int n = item >> 3, k8 = item & 7;
            s16x8 h;
#pragma unroll
            for (int i = 0; i < 8; i++) h[i] = (short)fbf(lds[(k8 * 8 + i) * 129 + n]);
            *(s16x8*)(dst + SWZ(n * 128 + k8 * 16)) = h;
        }
    }
}

// MFMA projection GEMM: C[640 x 1024] = W x X per batch. 128x128 tile, BK=64, dbuf LDS.
__global__ __launch_bounds__(256) void k_projm(
        const float* __restrict__ b1, const float* __restrict__ b2,
        const float* __restrict__ b3, float* __restrict__ ws) {
    __shared__ __align__(16) char smem[65536];
    int tid = threadIdx.x, lane = tid & 63, wv = tid >> 6;
    int lidx = lane & 15, q = lane >> 4;
    int mT = blockIdx.x, nT = blockIdx.y, b = blockIdx.z;
    int mh = wv >> 1, nh = wv & 1;
    const char* wtg = (const char*)(ws + OFF_WT) + mT * 8 * 16384;
    const char* xtg = (const char*)(ws + OFF_XT) + (b * 8 + nT) * 8 * 16384;

    f32x4 acc[4][4];
#pragma unroll
    for (int i = 0; i < 4; i++)
#pragma unroll
        for (int j = 0; j < 4; j++) acc[i][j] = (f32x4)0.f;

#define STAGE(kt, buf) do { \
        const char* ga_ = wtg + (kt) * 16384; \
        const char* gb_ = xtg + (kt) * 16384; \
        char* la_ = smem + (buf) * 32768; \
        char* lb_ = la_ + 16384; \
        _Pragma("unroll") \
        for (int c_ = 0; c_ < 4; c_++) { \
            GLD16(ga_ + c_ * 4096 + wv * 1024 + lane * 16, la_ + c_ * 4096 + wv * 1024); \
            GLD16(gb_ + c_ * 4096 + wv * 1024 + lane * 16, lb_ + c_ * 4096 + wv * 1024); \
        } \
    } while (0)

    STAGE(0, 0);
    __syncthreads();
    for (int kt = 0; kt < 8; kt++) {
        if (kt < 7) STAGE(kt + 1, (kt + 1) & 1);
        const char* la = smem + (kt & 1) * 32768;
        const char* lb = la + 16384;
#pragma unroll
        for (int ks = 0; ks < 2; ks++) {
            s16x8 af[4], bf[4];
            int kb = ks * 64 + q * 16;
#pragma unroll
            for (int f = 0; f < 4; f++) {
                int arow = mh * 64 + f * 16 + lidx;
                int brow = nh * 64 + f * 16 + lidx;
                af[f] = *(const s16x8*)(la + SWZ(arow * 128 + kb));
                bf[f] = *(const s16x8*)(lb + SWZ(brow * 128 + kb));
            }
#pragma unroll
            for (int mf = 0; mf < 4; mf++)
#pragma unroll
                for (int nf = 0; nf < 4; nf++)
                    acc[mf][nf] = __builtin_amdgcn_mfma_f32_16x16x32_bf16(
                        af[mf], bf[nf], acc[mf][nf], 0, 0, 0);
        }
        __syncthreads();
    }
#undef STAGE

    unsigned short* x1t = (unsigned short*)(ws + OFF_X1T);
    unsigned short* x2t = (unsigned short*)(ws + OFF_X2T);
    unsigned short* x3t = (unsigned short*)(ws + OFF_X3T);
#pragma unroll
    for (int mf = 0; mf < 4; mf++) {
        int mloc = mh * 64 + mf * 16 + q * 4;
        int mg = mT * 128 + mloc;
#pragma unroll
        for (int nf = 0; nf < 4; nf++) {
            int n = nT * 128 + nh * 64 + nf * 16 + lidx;
            float o[4];
            uint2 pk;
            if (mg < 64) {
#pragma unroll
                for (int r = 0; r < 4; r++)
                    o[r] = ws[OFF_A0 + mg + r] * (acc[mf][nf][r] + b1[mg + r]) + ws[OFF_C0 + mg + r];
                pk.x = pk2bf(o[0], o[1]); pk.y = pk2bf(o[2], o[3]);
                *(uint2*)(x1t + (size_t)(b * HWTOT + n) * 64 + mg) = pk;
            } else if (mg < 128) {
                int c = mg - 64;
#pragma unroll
                for (int r = 0; r < 4; r++)
                    o[r] = ws[OFF_A0 + c + r] * (acc[mf][nf][r] + b2[c + r]);
                pk.x = pk2bf(o[0], o[1]); pk.y = pk2bf(o[2], o[3]);
                *(uint2*)(x2t + (size_t)(b * HWTOT + n) * 64 + c) = pk;
            } else {
                int c = mg - 128;
#pragma unroll
                for (int r = 0; r < 4; r++)
                    o[r] = acc[mf][nf][r] + b3[c + r];
                pk.x = pk2bf(o[0], o[1]); pk.y = pk2bf(o[2], o[3]);
                *(uint2*)(x3t + (size_t)(b * HWTOT + n) * 512 + c) = pk;
            }
        }
    }
}

// Fallback fp32 projection (used only if ws_size is too small for tiles); bf16 outputs.
__global__ __launch_bounds__(256) void k_proj(
        const float* __restrict__ x,
        const float* __restrict__ w1, const float* __restrict__ b1,
        const float* __restrict__ w2, const float* __restrict__ b2,
        const float* __restrict__ w3, const float* __restrict__ b3,
        float* __restrict__ ws) {
    __shared__ __align__(16) float As[64 * 17];
    __shared__ __align__(16) float Bs[16 * 64];
    int tid = threadIdx.x;
    int n0 = blockIdx.x * 64;
    int mT = blockIdx.y;
    int b = blockIdx.z;
    int mq = tid >> 4, nq = tid & 15;
    float acc[4][4];
#pragma unroll
    for (int i = 0; i < 4; i++)
#pragma unroll
        for (int j = 0; j < 4; j++) acc[i][j] = 0.f;

    for (int k0 = 0; k0 < CIN; k0 += 16) {
#pragma unroll
        for (int i = 0; i < 4; i++) {
            int t = tid + i * 256;
            int k = t & 15, m = t >> 4;
            int mg = mT * 64 + m;
            const float* Wrow;
            if (mg < 64) Wrow = w1 + mg * CIN;
            else if (mg < 128) Wrow = w2 + (mg - 64) * CIN;
            else Wrow = w3 + (mg - 128) * CIN;
            As[m * 17 + k] = Wrow[k0 + k];
        }
#pragma unroll
        for (int i = 0; i < 4; i++) {
            int t = tid + i * 256;
            int n = t & 63, k = t >> 6;
            Bs[k * 64 + n] = x[(b * CIN + k0 + k) * HWTOT + n0 + n];
        }
        __syncthreads();
#pragma unroll
        for (int k = 0; k < 16; k++) {
            float4 bv = *(const float4*)&Bs[k * 64 + nq * 4];
            float av[4];
#pragma unroll
            for (int i = 0; i < 4; i++) av[i] = As[(mq * 4 + i) * 17 + k];
#pragma unroll
            for (int i = 0; i < 4; i++) {
                acc[i][0] += av[i] * bv.x;
                acc[i][1] += av[i] * bv.y;
                acc[i][2] += av[i] * bv.z;
                acc[i][3] += av[i] * bv.w;
            }
        }
        __syncthreads();
    }
    unsigned short* x1t = (unsigned short*)(ws + OFF_X1T);
    unsigned short* x2t = (unsigned short*)(ws + OFF_X2T);
    unsigned short* x3t = (unsigned short*)(ws + OFF_X3T);
#pragma unroll
    for (int i = 0; i < 4; i++) {
        int mg = mT * 64 + mq * 4 + i;
        if (mg < 64) {
            float bias = b1[mg];
            float aa = ws[OFF_A0 + mg], cc = ws[OFF_C0 + mg];
#pragma unroll
            for (int j = 0; j < 4; j++) {
                int n = n0 + nq * 4 + j;
                x1t[(size_t)(b * HWTOT + n) * 64 + mg] = fbf(aa * (acc[i][j] + bias) + cc);
            }
        } else if (mg < 128) {
            int r = mg - 64;
            float bias = b2[r];
            float aa = ws[OFF_A0 + r];
#pragma unroll
            for (int j = 0; j < 4; j++) {
                int n = n0 + nq * 4 + j;
                x2t[(size_t)(b * HWTOT + n) * 64 + r] = fbf(aa * (acc[i][j] + bias));
            }
        } else {
            float bias = b3[mg - 128];
#pragma unroll
            for (int j = 0; j < 4; j++) {
                int n = n0 + nq * 4 + j;
                x3t[(size_t)(b * HWTOT + n) * 512 + (mg - 128)] = fbf(acc[i][j] + bias);
            }
        }
    }
}

// One wave = one pixel = one workgroup (64 threads). No barriers. XCD-chunked swizzle.
__global__ __launch_bounds__(64, 4) void k_fused(
        const float* __restrict__ ws, float* __restrict__ out) {
    __shared__ __align__(16) char smem[8960];  // t1/wgt 8KB + aux 768B

    int lane = threadIdx.x;
    int lidx = lane & 15;
    int q = lane >> 4;

    int bid = blockIdx.x;
    int p = (bid & 7) * 512 + (bid >> 3);   // XCD k -> contiguous 512-pixel chunk
    int b = p >> 10;
    int n = p & 1023;
    int y = n >> 5, x0 = n & 31;

    char* t1p = smem;                        // t1 [64col][64co] bf16 SWZ; later wgt [64g][64k] bf16 SWZ
    float* auxf = (float*)(smem + 8192);     // s64[64], s65[64]
    int* nbo = (int*)(smem + 8704);          // nbo[64]

    const unsigned short* x1t = (const unsigned short*)(ws + OFF_X1T);
    const unsigned short* x2t = (const unsigned short*)(ws + OFF_X2T);
    const unsigned short* x3t = (const unsigned short*)(ws + OFF_X3T);
    const float* pm  = ws + OFF_PM;
    const unsigned short* w1b = (const unsigned short*)(ws + OFF_W1B);
    const unsigned short* w2f = (const unsigned short*)(ws + OFF_W2F);

    // ---- per-lane neighbor precompute (k = lane) ----
    {
        int k = lane;
        int di = k / 7 - 3, dj = k % 7 - 3;
        int nb = refl(y + di) * 32 + refl(x0 + dj);
        nbo[k] = nb;
        float a064 = ws[OFF_A0 + 64], c064 = ws[OFF_C0 + 64];
        float a065 = ws[OFF_A0 + 65], c065 = ws[OFF_C0 + 65];
        auxf[k]      = fmaxf(fmaf(a064, pm[n * 2 + 0] - pm[nb * 2 + 0], c064), 0.f);
        auxf[64 + k] = fmaxf(fmaf(a065, pm[n * 2 + 1] - pm[nb * 2 + 1], c065), 0.f);
    }
    asm volatile("s_waitcnt lgkmcnt(0)" ::: "memory");
    __builtin_amdgcn_sched_barrier(0);

    // ---- A-frags (wcw1) + x1 registers ----
    s16x8 af1[4][2];
#pragma unroll
    for (int cot = 0; cot < 4; cot++)
#pragma unroll
        for (int ks = 0; ks < 2; ks++)
            af1[cot][ks] = *(const s16x8*)(w1b + (lidx + 16 * cot) * 64 + ks * 32 + q * 8);

    const unsigned short* x1r = x1t + (size_t)(b * HWTOT + n) * 64 + q * 8;
    float x1f[2][8];
    {
        s16x8 h0 = *(const s16x8*)(x1r);
        s16x8 h1 = *(const s16x8*)(x1r + 32);
#pragma unroll
        for (int i = 0; i < 8; i++) {
            x1f[0][i] = bf2f((unsigned short)h0[i]);
            x1f[1][i] = bf2f((unsigned short)h1[i]);
        }
    }

    // ---- GEMM1: per col-tile build B in regs, MFMA, epilogue -> t1 LDS ----
#pragma unroll
    for (int ct = 0; ct < 4; ct++) {
        int col = lidx + 16 * ct;
        int nb = nbo[col];
        const unsigned short* x2r = x2t + (size_t)(b * HWTOT + nb) * 64 + q * 8;
        f32x4 acc1[4];
#pragma unroll
        for (int cot = 0; cot < 4; cot++) acc1[cot] = (f32x4)0.f;
#pragma unroll
        for (int ks = 0; ks < 2; ks++) {
            s16x8 v = *(const s16x8*)(x2r + ks * 32);
            union { s16x8 v; unsigned u[4]; } bb;
#pragma unroll
            for (int w = 0; w < 4; w++)
                bb.u[w] = pk2bf(
                    fmaxf(x1f[ks][2 * w]     - bf2f((unsigned short)v[2 * w]),     0.f),
                    fmaxf(x1f[ks][2 * w + 1] - bf2f((unsigned short)v[2 * w + 1]), 0.f));
#pragma unroll
            for (int cot = 0; cot < 4; cot++)
                acc1[cot] = __builtin_amdgcn_mfma_f32_16x16x32_bf16(af1[cot][ks], bb.v, acc1[cot], 0, 0, 0);
        }
        float s64 = auxf[col], s65 = auxf[64 + col];
#pragma unroll
        for (int cot = 0; cot < 4; cot++) {
            f32x4 wa = *(const f32x4*)(ws + OFF_W64 + cot * 16 + q * 4);
            f32x4 wb = *(const f32x4*)(ws + OFF_W65 + cot * 16 + q * 4);
            f32x4 cc = *(const f32x4*)(ws + OFF_C1V + cot * 16 + q * 4);
            float t[4];
#pragma unroll
            for (int r = 0; r < 4; r++)
                t[r] = fmaxf(acc1[cot][r] + wa[r] * s64 + wb[r] * s65 + cc[r], 0.f);
            uint2 pk;
            pk.x = pk2bf(t[0], t[1]);
            pk.y = pk2bf(t[2], t[3]);
            int byte = col * 128 + cot * 32 + q * 8;
            *(uint2*)(t1p + SWZ(byte)) = pk;
        }
    }

    asm volatile("s_waitcnt lgkmcnt(0)" ::: "memory");
    __builtin_amdgcn_sched_barrier(0);

    // ---- GEMM2 (swapped operands: D[k][g]) + softmax over k, per g-tile ----
    s16x8 af2[4][2];
#pragma unroll
    for (int gt = 0; gt < 4; gt++)
#pragma unroll
        for (int ks2 = 0; ks2 < 2; ks2++)
            af2[gt][ks2] = *(const s16x8*)(w2f + ((gt * 2 + ks2) * 64 + lane) * 8);

    unsigned held[4][4][2];
#pragma unroll
    for (int gt = 0; gt < 4; gt++) {
        f32x4 acc2[4];
#pragma unroll
        for (int kt = 0; kt < 4; kt++) acc2[kt] = (f32x4)0.f;
#pragma unroll
        for (int kt = 0; kt < 4; kt++) {
#pragma unroll
            for (int ks2 = 0; ks2 < 2; ks2++) {
                int byte = (lidx + 16 * kt) * 128 + ks2 * 64 + q * 16;
                s16x8 a = *(const s16x8*)(t1p + SWZ(byte));
                acc2[kt] = __builtin_amdgcn_mfma_f32_16x16x32_bf16(a, af2[gt][ks2], acc2[kt], 0, 0, 0);
            }
        }
        float mx = -1e30f;
#pragma unroll
        for (int kt = 0; kt < 3; kt++)
#pragma unroll
            for (int r = 0; r < 4; r++) mx = fmaxf(mx, acc2[kt][r]);
        if (q == 0) mx = fmaxf(mx, acc2[3][0]);
        mx = fmaxf(mx, __shfl_xor(mx, 16));
        mx = fmaxf(mx, __shfl_xor(mx, 32));
        float e[4][4];
        float sum = 0.f;
#pragma unroll
        for (int kt = 0; kt < 4; kt++)
#pragma unroll
            for (int r = 0; r < 4; r++) {
                bool valid = (kt < 3) || (q == 0 && r == 0);
                float ev = valid ? exp2f((acc2[kt][r] - mx) * 1.44269504f) : 0.f;
                e[kt][r] = ev;
                sum += ev;
            }
        sum += __shfl_xor(sum, 16);
        sum += __shfl_xor(sum, 32);
        float inv = 1.f / sum;
#pragma unroll
        for (int kt = 0; kt < 4; kt++) {
            held[gt][kt][0] = pk2bf(e[kt][0] * inv, e[kt][1] * inv);
            held[gt][kt][1] = pk2bf(e[kt][2] * inv, e[kt][3] * inv);
        }
    }

    // all t1 reads done -> overwrite buffer with wgt [g][k] bf16
#pragma unroll
    for (int gt = 0; gt < 4; gt++)
#pragma unroll
        for (int kt = 0; kt < 4; kt++) {
            int byte = (lidx + 16 * gt) * 128 + kt * 32 + q * 8;
            uint2 pk;
            pk.x = held[gt][kt][0];
            pk.y = held[gt][kt][1];
            *(uint2*)(t1p + SWZ(byte)) = pk;
        }

    asm volatile("s_waitcnt lgkmcnt(0)" ::: "memory");
    __builtin_amdgcn_sched_barrier(0);

    // ---- aggregation: lane owns 8 channels (g = lane), wgt row pre-read ----
    s16x8 wrow[7];
#pragma unroll
    for (int i = 0; i < 7; i++)
        wrow[i] = *(const s16x8*)(t1p + SWZ(lane * 128 + i * 16));

    f32x4 a30 = (f32x4)0.f, a31 = (f32x4)0.f;
    const unsigned short* x3b = x3t + (size_t)b * HWTOT * 512 + lane * 8;
#pragma unroll
    for (int k = 0; k < KKW; k++) {
        int nb = nbo[k];
        float w = bf2f((unsigned short)wrow[k >> 3][k & 7]);
        s16x8 v = *(const s16x8*)(x3b + (size_t)nb * 512);
#pragma unroll
        for (int r = 0; r < 4; r++) {
            a30[r] = fmaf(w, bf2f((unsigned short)v[r]), a30[r]);
            a31[r] = fmaf(w, bf2f((unsigned short)v[4 + r]), a31[r]);
        }
    }
    float* ob = out + ((size_t)b * COUT + lane * 8) * HWTOT + n;
#pragma unroll
    for (int i = 0; i < 4; i++) ob[i * HWTOT] = a30[i];
#pragma unroll
    for (int i = 0; i < 4; i++) ob[(i + 4) * HWTOT] = a31[i];
}

extern "C" void kernel_launch(void* const* d_in, const int* in_sizes, int n_in,
                              void* d_out, int out_size, void* d_ws, size_t ws_size,
                              hipStream_t stream) {
    const float* x = (const float*)d_in[0];
    const float* w1 = (const float*)d_in[1];
    const float* b1 = (const float*)d_in[2];
    const float* w2 = (const float*)d_in[3];
    const float* b2 = (const float*)d_in[4];
    const float* w3 = (const float*)d_in[5];
    const float* b3 = (const float*)d_in[6];
    const float* wp = (const float*)d_in[7];
    const float* bp = (const float*)d_in[8];
    const float* g0 = (const float*)d_in[9];
    const float* be0 = (const float*)d_in[10];
    const float* m0 = (const float*)d_in[11];
    const float* v0 = (const float*)d_in[12];
    const float* wcw1 = (const float*)d_in[13];
    const float* g1 = (const float*)d_in[14];
    const float* be1 = (const float*)d_in[15];
    const float* m1 = (const float*)d_in[16];
    const float* v1 = (const float*)d_in[17];
    const float* wcw2 = (const float*)d_in[18];
    float* ws = (float*)d_ws;
    float* out = (float*)d_out;

    if (ws_size >= WS_NEED_FLOATS * 4ull) {
        k_prep<<<297, 256, 0, stream>>>(x, w1, w2, w3, wp, bp, g0, be0, m0, v0,
                                        wcw1, g1, be1, m1, v1, wcw2, ws);
        k_projm<<<dim3(5, 8, 4), 256, 0, stream>>>(b1, b2, b3, ws);
    } else {
        k_setup<<<1, 256, 0, stream>>>(wp, bp, g0, be0, m0, v0, wcw1, g1, be1, m1, v1, wcw2, ws);
        k_proj<<<dim3(16, 10, 4), 256, 0, stream>>>(x, w1, b1, w2, b2, w3, b3, ws);
    }
    k_fused<<<4096, 64, 0, stream>>>(ws, out);
}